// Round 17
// baseline (228.229 us; speedup 1.0000x reference)
//
#include <hip/hip_runtime.h>
#include <hip/hip_bf16.h>

#define NAG 3
#define BATCH 32768
#define HD 128
#define SD 18
#define ROWS 48
#define NBLK 683
#define PADB (NBLK * ROWS)     // 32784
#define EPSV 1e-5f
#define SCALE 0.08838834764831845f

typedef __attribute__((ext_vector_type(8))) short short8;
typedef __attribute__((ext_vector_type(4))) float f32x4;

// ---------------- ws byte layout ----------------
#define WSB_STATS 0
#define WSB_ACCUM 512
#define WSB_F     1024
#define WSB_W     197632
#define OFF_FT0 0
#define OFF_FT1 32768
#define OFF_MT  65536
#define OFF_AV0 98304
#define OFF_AV1 131072
#define OFF_CV  163840
#define OFF_MG(n) (196608 + (n)*98304)
#define OFF_C1(n) (491520 + (n)*65536)
#define OFF_C2(n) (688128 + (n)*4096)
#define OFF_SW(n) (700416 + (n)*57344)
#define WSB_SA  2097152
#define SA_BYTES_P ((size_t)NAG * PADB * HD * 2)

__device__ __forceinline__ float lrelu(float x){ return x >= 0.0f ? x : 0.01f * x; }
__device__ __forceinline__ f32x4 lrelu4(f32x4 v){
  f32x4 r; r[0]=lrelu(v[0]); r[1]=lrelu(v[1]); r[2]=lrelu(v[2]); r[3]=lrelu(v[3]); return r;
}
__device__ __forceinline__ f32x4 binit(float b){ f32x4 c; c[0]=b;c[1]=b;c[2]=b;c[3]=b; return c; }
__device__ __forceinline__ unsigned short f2bf(float f){
  __hip_bfloat16 h = __float2bfloat16(f);     // HW v_cvt (RNE)
  return *reinterpret_cast<unsigned short*>(&h);
}
__device__ __forceinline__ float bf2f(unsigned short h){
  return __uint_as_float(((unsigned int)h) << 16);
}

// ---------------- prep: batch stats (384 blocks: full-device BW) ----------------
__global__ void stats_partial_kernel(const float* __restrict__ s,
                                     const float* __restrict__ a,
                                     float* __restrict__ accum){
  const int n = blockIdx.x >> 7;        // 3 agents x 128 chunks
  const int chunk = blockIdx.x & 127;
  const int t = threadIdx.x;
  const int rows = BATCH / 128;         // 256
  const int b0 = chunk * rows;
  float sum[20], sq[20];
  #pragma unroll
  for (int c = 0; c < 20; ++c){ sum[c] = 0.f; sq[c] = 0.f; }
  for (int b = b0 + t; b < b0 + rows; b += 256){
    const float* row = s + ((size_t)n * BATCH + b) * SD;
    #pragma unroll
    for (int c = 0; c < SD; ++c){ float v = row[c]; sum[c] += v; sq[c] += v * v; }
    const float* ra = a + ((size_t)n * BATCH + b) * 2;
    #pragma unroll
    for (int c = 0; c < 2; ++c){ float v = ra[c]; sum[SD + c] += v; sq[SD + c] += v * v; }
  }
  __shared__ float red[256];
  for (int c = 0; c < 20; ++c){
    red[t] = sum[c]; __syncthreads();
    for (int off = 128; off > 0; off >>= 1){ if (t < off) red[t] += red[t + off]; __syncthreads(); }
    if (t == 0) atomicAdd(&accum[(n * 20 + c) * 2 + 0], red[0]);
    __syncthreads();
    red[t] = sq[c]; __syncthreads();
    for (int off = 128; off > 0; off >>= 1){ if (t < off) red[t] += red[t + off]; __syncthreads(); }
    if (t == 0) atomicAdd(&accum[(n * 20 + c) * 2 + 1], red[0]);
    __syncthreads();
  }
}

// ---------------- prep: F_m = sel @ key^T + stats finalize ----------------
__global__ void fuse_mats_kernel(const float* __restrict__ asel, const float* __restrict__ akey,
                                 const float* __restrict__ csel, const float* __restrict__ ckey,
                                 float* __restrict__ F, const float* __restrict__ accum,
                                 float* __restrict__ stats){
  const int m  = blockIdx.y;
  if (m == 3){
    if (blockIdx.x == 0){
      int i = threadIdx.x;
      if (i < 60){
        float S = accum[i * 2 + 0], SQ = accum[i * 2 + 1];
        float mean = S / (float)BATCH;
        float var = SQ / (float)BATCH - mean * mean;
        stats[i * 2 + 0] = mean;
        stats[i * 2 + 1] = 1.0f / sqrtf(var + EPSV);
      }
    }
    return;
  }
  const int h1 = blockIdx.x;
  const int h2 = threadIdx.x;
  const float* A; const float* Bm;
  if (m == 0){ A = asel;            Bm = akey; }
  else if (m == 1){ A = asel + HD*HD; Bm = akey + HD*HD; }
  else { A = csel; Bm = ckey; }
  const float* arow = A + h1 * HD;
  const float* brow = Bm + h2 * HD;
  float acc = 0.f;
  #pragma unroll 4
  for (int d = 0; d < HD; ++d) acc = fmaf(arow[d], brow[d], acc);
  F[m * HD * HD + h1 * HD + h2] = acc;
}

// ---------------- prep: all weight splits + smallpack ----------------
__global__ void prep_split_kernel(const float* __restrict__ F, const float* __restrict__ aval_W,
                                  const float* __restrict__ cval_W, const float* __restrict__ merge_W,
                                  const float* __restrict__ cW1, const float* __restrict__ cW2,
                                  const float* __restrict__ en_W, const float* __restrict__ oa_W,
                                  const float* __restrict__ goal_W, const float* __restrict__ senc_W,
                                  unsigned short* __restrict__ wsu){
  const int job = blockIdx.y;
  const int idx = blockIdx.x * 256 + threadIdx.x;
  if (job == 15){
    if (idx >= 3 * 896 * 32) return;
    int k = idx & 31; int c = (idx >> 5) % 896; int n = idx / (896 * 32);
    int tt = c >> 7, cc = c & 127;
    float v = 0.f;
    if (tt == 0){
      if (k < 4) v = en_W[(size_t)(n*6 + k)*128 + cc];
      else if (k == 18 || k == 19) v = en_W[(size_t)(n*6 + 4 + (k-18))*128 + cc];
    } else if (tt <= 2){
      int j = tt - 1; int kk = k - (4 + 4*j);
      if (kk >= 0 && kk < 4) v = oa_W[(size_t)(n*4 + kk)*128 + cc];
    } else if (tt <= 5){
      int j = tt - 3; int kk = k - (12 + 2*j);
      if (kk >= 0 && kk < 2) v = goal_W[(size_t)(n*2 + kk)*128 + cc];
    } else {
      if (k < 18) v = senc_W[(size_t)(n*18 + k)*128 + cc];
    }
    unsigned short hi = f2bf(v); float lo = v - bf2f(hi);
    unsigned short* dh = wsu + OFF_SW(n);
    dh[c * 32 + k] = hi;
    dh[28672 + c * 32 + k] = f2bf(lo);
    return;
  }
  const float* src; unsigned short* dh; int K = 128, Csrc = 128, Cdst = 128, loff = 16384;
  switch (job){
    case 0: src = F;              dh = wsu + OFF_FT0; break;
    case 1: src = F + 16384;      dh = wsu + OFF_FT1; break;
    case 2: src = F + 32768;      dh = wsu + OFF_MT;  break;
    case 3: src = aval_W;         dh = wsu + OFF_AV0; break;
    case 4: src = aval_W + 16384; dh = wsu + OFF_AV1; break;
    case 5: src = cval_W;         dh = wsu + OFF_CV;  break;
    case 6: case 7: case 8: {
      int n = job - 6; src = merge_W + (size_t)n * 49152; dh = wsu + OFF_MG(n);
      K = 384; loff = 49152; } break;
    case 9: case 10: case 11: {
      int n = job - 9; src = cW1 + (size_t)n * 32768; dh = wsu + OFF_C1(n);
      K = 256; loff = 32768; } break;
    default: {
      int n = job - 12; src = cW2 + (size_t)n * 256; dh = wsu + OFF_C2(n);
      Csrc = 2; Cdst = 16; loff = 2048; } break;
  }
  if (idx >= K * Cdst) return;
  int k = idx / Cdst, c = idx - k * Cdst;
  float v = (c < Csrc) ? src[(size_t)k * Csrc + c] : 0.f;
  unsigned short hi = f2bf(v);
  dh[(size_t)c * K + k] = hi;
  dh[loff + (size_t)c * K + k] = f2bf(v - bf2f(hi));
}

// ---------------- MFMA helpers ----------------
__device__ __forceinline__ short8 ldAh(const unsigned char* sm, int base, int mi, int ks, int lane){
  int row = mi * 16 + (lane & 15);
  int bc  = ks * 64 + ((lane >> 4) << 4);
  return *(const short8*)(sm + base + row * 256 + (bc ^ ((row & 7) << 4)));
}
__device__ __forceinline__ short8 ldA32h(const unsigned char* sm, int base, int mi, int lane){
  int row = mi * 16 + (lane & 15);
  int bc  = (lane >> 4) << 4;
  return *(const short8*)(sm + base + row * 64 + (bc ^ ((row & 3) << 4)));
}

#define MM1(acc, ah, bh) \
  acc = __builtin_amdgcn_mfma_f32_16x16x32_bf16(ah, bh, acc, 0, 0, 0);

// hi-A, hi-B small encoder: 1 MFMA/mt
__device__ __forceinline__ void gemmS3_hh(f32x4& c0, f32x4& c1, f32x4& c2,
                                          const unsigned char* sm, int abase,
                                          const unsigned short* wh, int bcol, int lane){
  const size_t bb = (size_t)bcol * 32 + ((lane >> 4) << 3);
  const short8 bh = *(const short8*)(wh + bb);
  MM1(c0, ldA32h(sm, abase, 0, lane), bh);
  MM1(c1, ldA32h(sm, abase, 1, lane), bh);
  MM1(c2, ldA32h(sm, abase, 2, lane), bh);
}
__device__ __forceinline__ void gemmAW2_3(f32x4& k0, f32x4& k1, f32x4& k2,
                                          f32x4& m0, f32x4& m1, f32x4& m2,
                                          const unsigned char* sm, int abase,
                                          const unsigned short* wh0, const unsigned short* wh1,
                                          int bcol, int lane){
  const size_t bb = (size_t)bcol * 128 + ((lane >> 4) << 3);
  #pragma unroll
  for (int ks = 0; ks < 4; ++ks){
    short8 a0 = ldAh(sm, abase, 0, ks, lane);
    short8 a1 = ldAh(sm, abase, 1, ks, lane);
    short8 a2 = ldAh(sm, abase, 2, ks, lane);
    const short8 b0 = *(const short8*)(wh0 + bb + ks * 32);
    const short8 b1 = *(const short8*)(wh1 + bb + ks * 32);
    MM1(k0, a0, b0); MM1(k1, a1, b0); MM1(k2, a2, b0);
    MM1(m0, a0, b1); MM1(m1, a1, b1); MM1(m2, a2, b1);
  }
}
__device__ __forceinline__ void gemmA2s3(f32x4& c0, f32x4& c1, f32x4& c2,
                                         f32x4& d0, f32x4& d1, f32x4& d2,
                                         const unsigned char* sm, int a0b, int a1b,
                                         const unsigned short* wh, int bcol, int lane){
  const size_t bb = (size_t)bcol * 128 + ((lane >> 4) << 3);
  #pragma unroll
  for (int ks = 0; ks < 4; ++ks){
    const short8 bh = *(const short8*)(wh + bb + ks * 32);
    short8 x;
    x = ldAh(sm, a0b, 0, ks, lane); MM1(c0, x, bh);
    x = ldAh(sm, a0b, 1, ks, lane); MM1(c1, x, bh);
    x = ldAh(sm, a0b, 2, ks, lane); MM1(c2, x, bh);
    x = ldAh(sm, a1b, 0, ks, lane); MM1(d0, x, bh);
    x = ldAh(sm, a1b, 1, ks, lane); MM1(d1, x, bh);
    x = ldAh(sm, a1b, 2, ks, lane); MM1(d2, x, bh);
  }
}
__device__ __forceinline__ void gemmA3s3(f32x4& c0, f32x4& c1, f32x4& c2,
                                         f32x4& d0, f32x4& d1, f32x4& d2,
                                         f32x4& e0, f32x4& e1, f32x4& e2,
                                         const unsigned char* sm, int a0b, int a1b, int a2b,
                                         const unsigned short* wh, int bcol, int lane){
  const size_t bb = (size_t)bcol * 128 + ((lane >> 4) << 3);
  #pragma unroll
  for (int ks = 0; ks < 4; ++ks){
    const short8 bh = *(const short8*)(wh + bb + ks * 32);
    short8 x;
    x = ldAh(sm, a0b, 0, ks, lane); MM1(c0, x, bh);
    x = ldAh(sm, a0b, 1, ks, lane); MM1(c1, x, bh);
    x = ldAh(sm, a0b, 2, ks, lane); MM1(c2, x, bh);
    x = ldAh(sm, a1b, 0, ks, lane); MM1(d0, x, bh);
    x = ldAh(sm, a1b, 1, ks, lane); MM1(d1, x, bh);
    x = ldAh(sm, a1b, 2, ks, lane); MM1(d2, x, bh);
    x = ldAh(sm, a2b, 0, ks, lane); MM1(e0, x, bh);
    x = ldAh(sm, a2b, 1, ks, lane); MM1(e1, x, bh);
    x = ldAh(sm, a2b, 2, ks, lane); MM1(e2, x, bh);
  }
}
__device__ __forceinline__ void gemmAh_hb3K(f32x4& c0, f32x4& c1, f32x4& c2,
                                            const unsigned char* sm, int abase,
                                            const unsigned short* wh,
                                            int K, int bcol, int kBase, int lane){
  const size_t bb = (size_t)bcol * K + kBase + ((lane >> 4) << 3);
  #pragma unroll
  for (int ks = 0; ks < 4; ++ks){
    const short8 bh = *(const short8*)(wh + bb + ks * 32);
    short8 a;
    a = ldAh(sm, abase, 0, ks, lane); MM1(c0, a, bh);
    a = ldAh(sm, abase, 1, ks, lane); MM1(c1, a, bh);
    a = ldAh(sm, abase, 2, ks, lane); MM1(c2, a, bh);
  }
}
__device__ __forceinline__ void gemmAh_hb3(f32x4& c0, f32x4& c1, f32x4& c2,
                                           const unsigned char* sm, int abase,
                                           const unsigned short* wh, int bcol, int lane){
  const size_t bb = (size_t)bcol * 128 + ((lane >> 4) << 3);
  #pragma unroll
  for (int ks = 0; ks < 4; ++ks){
    const short8 bh = *(const short8*)(wh + bb + ks * 32);
    short8 a;
    a = ldAh(sm, abase, 0, ks, lane); MM1(c0, a, bh);
    a = ldAh(sm, abase, 1, ks, lane); MM1(c1, a, bh);
    a = ldAh(sm, abase, 2, ks, lane); MM1(c2, a, bh);
  }
}

// stores
__device__ __forceinline__ void stH(unsigned char* sm, int base, int mi, int lane, int col, f32x4 v){
  #pragma unroll
  for (int r = 0; r < 4; ++r){
    int row = mi * 16 + ((lane >> 4) << 2) + r;
    int off = base + row * 256 + ((col * 2) ^ ((row & 7) << 4));
    *(unsigned short*)(sm + off) = f2bf(v[r]);
  }
}
__device__ __forceinline__ void stSK(unsigned char* sm, int base, int mi, int lane, int col, f32x4 v){
  #pragma unroll
  for (int r = 0; r < 4; ++r){
    int row = mi * 16 + ((lane >> 4) << 2) + r;
    int off = base + row * 256 + ((col * 2) ^ ((row & 7) << 5));
    *(unsigned short*)(sm + off) = f2bf(v[r]);
  }
}
__device__ __forceinline__ float dot8(short8 x, short8 y){
  float acc = 0.f;
  #pragma unroll
  for (int e = 0; e < 8; ++e)
    acc = fmaf(bf2f((unsigned short)x[e]), bf2f((unsigned short)y[e]), acc);
  return acc;
}
#define RED8(p) { p += __shfl_xor(p, 1); p += __shfl_xor(p, 2); p += __shfl_xor(p, 4); }

// ======================================================================
// PATH A: actor kernel — grid (NBLK, NAG), 512 threads, ROWS=48, 77.6KB LDS
// (XN hi-only)
// ======================================================================
__global__ __launch_bounds__(512, 4) void actor_kernel(
    const float* __restrict__ s, const float* __restrict__ a,
    const float* __restrict__ en_b, const float* __restrict__ oa_b,
    const float* __restrict__ goal_b, const float* __restrict__ aval_b,
    const float* __restrict__ merge_b, const unsigned char* __restrict__ wsc,
    unsigned short* __restrict__ sa_g)
{
  __shared__ __align__(16) unsigned char SM[77568];
  const int AXN = 0, AEN = 3072, AOV = 15360, ASK = 27648;
  const int SLB0 = 39936, SLB1 = 52224, SLB2 = 64512, AEP = 76800;
  const int t = threadIdx.x, lane = t & 63, wave = t >> 6;
  const int col = wave * 16 + (lane & 15);
  const int n = blockIdx.y;
  const int gb0 = blockIdx.x * ROWS;
  const float* stats = (const float*)(wsc + WSB_STATS);
  const unsigned short* wsu = (const unsigned short*)(wsc + WSB_W);
  const unsigned short* swh = wsu + OFF_SW(n);
  float* eP0 = (float*)(SM + AEP);
  float* eP1 = eP0 + 48;
  float* eP2 = eP0 + 96;
  float* esm = eP0 + 144;
  const f32x4 Z = binit(0.f);
  const int drow = wave * 8 + (lane >> 3);
  const int dcb  = (lane & 7) * 32;
  const int r0base = (lane >> 4) << 2;

  // init: stage normalized XN (hi-only, K=32), clamped reads
  if (t < ROWS){
    int row = t;
    size_t gb = (size_t)gb0 + row;
    if (gb >= BATCH) gb = BATCH - 1;
    const float* st = stats + n * 40;
    const float* srow = s + ((size_t)n * BATCH + gb) * SD;
    const float* arow = a + ((size_t)n * BATCH + gb) * 2;
    #pragma unroll
    for (int c = 0; c < 32; ++c){
      float v = 0.f;
      if (c < 18) v = (srow[c] - st[c*2]) * st[c*2+1];
      else if (c < 20) v = (arow[c-18] - st[c*2]) * st[c*2+1];
      int off = AXN + row * 64 + ((c * 2) ^ ((row & 3) << 4));
      *(unsigned short*)(SM + off) = f2bf(v);
    }
  }
  __syncthreads();
  // R0: en_enc -> AEN ; oa slices -> SLB0, SLB1 (hi-A hi-B)
  {
    f32x4 c0 = binit(en_b[n*HD + col]), c1 = c0, c2 = c0;
    gemmS3_hh(c0, c1, c2, SM, AXN, swh, col, lane);
    stH(SM, AEN, 0, lane, col, lrelu4(c0));
    stH(SM, AEN, 1, lane, col, lrelu4(c1));
    stH(SM, AEN, 2, lane, col, lrelu4(c2));
    const float bb = oa_b[n*HD + col];
    c0 = binit(bb); c1 = c0; c2 = c0;
    gemmS3_hh(c0, c1, c2, SM, AXN, swh, 128 + col, lane);
    stH(SM, SLB0, 0, lane, col, lrelu4(c0));
    stH(SM, SLB0, 1, lane, col, lrelu4(c1));
    stH(SM, SLB0, 2, lane, col, lrelu4(c2));
    c0 = binit(bb); c1 = c0; c2 = c0;
    gemmS3_hh(c0, c1, c2, SM, AXN, swh, 256 + col, lane);
    stH(SM, SLB1, 0, lane, col, lrelu4(c0));
    stH(SM, SLB1, 1, lane, col, lrelu4(c1));
    stH(SM, SLB1, 2, lane, col, lrelu4(c2));
  }
  __syncthreads();
  // R1: selk0 -> AOV, selk1 -> ASK (hi-B)
  {
    f32x4 k0 = Z, k1 = Z, k2 = Z, m0 = Z, m1 = Z, m2 = Z;
    gemmAW2_3(k0, k1, k2, m0, m1, m2, SM, AEN,
              wsu + OFF_FT0, wsu + OFF_FT1, col, lane);
    stSK(SM, AOV, 0, lane, col, k0); stSK(SM, AOV, 1, lane, col, k1); stSK(SM, AOV, 2, lane, col, k2);
    stSK(SM, ASK, 0, lane, col, m0); stSK(SM, ASK, 1, lane, col, m1); stSK(SM, ASK, 2, lane, col, m2);
  }
  __syncthreads();
  // R2: oa vals + logit dots + exp
  f32x4 va0, va1, va2, vb0, vb1, vb2;
  {
    const float vb = aval_b[col];
    va0 = binit(vb); va1 = va0; va2 = va0; vb0 = va0; vb1 = va0; vb2 = va0;
    gemmA2s3(va0, va1, va2, vb0, vb1, vb2, SM, SLB0, SLB1, wsu + OFF_AV0, col, lane);
    if (drow < ROWS){
      int sw5 = (drow & 7) << 5, sw4 = (drow & 7) << 4;
      const unsigned char* kb = SM + AOV + drow * 256;
      short8 kfa = *(const short8*)(kb + (dcb ^ sw5));
      short8 kfb = *(const short8*)(kb + ((dcb + 16) ^ sw5));
      const unsigned char* s0 = SM + SLB0 + drow * 256;
      short8 e0a = *(const short8*)(s0 + (dcb ^ sw4));
      short8 e0b = *(const short8*)(s0 + ((dcb + 16) ^ sw4));
      const unsigned char* s1 = SM + SLB1 + drow * 256;
      short8 e1a = *(const short8*)(s1 + (dcb ^ sw4));
      short8 e1b = *(const short8*)(s1 + ((dcb + 16) ^ sw4));
      float p0 = dot8(kfa, e0a) + dot8(kfb, e0b);
      float p1 = dot8(kfa, e1a) + dot8(kfb, e1b);
      RED8(p0) RED8(p1)
      if ((lane & 7) == 0){
        float e0 = __expf(p0 * SCALE), e1 = __expf(p1 * SCALE);
        eP0[drow] = e0; eP1[drow] = e1; esm[drow] = e0 + e1;
      }
    }
  }
  __syncthreads();
  // R3: ov0 -> AOV ; goal slices g0,g1,g2 -> SLB0,1,2 (hi-A hi-B)
  {
    f32x4 o;
    #pragma unroll
    for (int r = 0; r < 4; ++r){
      int mr = r0base + r;
      o[r] = (eP0[mr] * lrelu(va0[r]) + eP1[mr] * lrelu(vb0[r])) / esm[mr];
    }
    stH(SM, AOV, 0, lane, col, o);
    #pragma unroll
    for (int r = 0; r < 4; ++r){
      int mr = 16 + r0base + r;
      o[r] = (eP0[mr] * lrelu(va1[r]) + eP1[mr] * lrelu(vb1[r])) / esm[mr];
    }
    stH(SM, AOV, 1, lane, col, o);
    #pragma unroll
    for (int r = 0; r < 4; ++r){
      int mr = 32 + r0base + r;
      o[r] = (eP0[mr] * lrelu(va2[r]) + eP1[mr] * lrelu(vb2[r])) / esm[mr];
    }
    stH(SM, AOV, 2, lane, col, o);
    const float bb = goal_b[n*HD + col];
    f32x4 c0 = binit(bb), c1 = c0, c2 = c0;
    gemmS3_hh(c0, c1, c2, SM, AXN, swh, 384 + col, lane);
    stH(SM, SLB0, 0, lane, col, lrelu4(c0));
    stH(SM, SLB0, 1, lane, col, lrelu4(c1));
    stH(SM, SLB0, 2, lane, col, lrelu4(c2));
    c0 = binit(bb); c1 = c0; c2 = c0;
    gemmS3_hh(c0, c1, c2, SM, AXN, swh, 512 + col, lane);
    stH(SM, SLB1, 0, lane, col, lrelu4(c0));
    stH(SM, SLB1, 1, lane, col, lrelu4(c1));
    stH(SM, SLB1, 2, lane, col, lrelu4(c2));
    c0 = binit(bb); c1 = c0; c2 = c0;
    gemmS3_hh(c0, c1, c2, SM, AXN, swh, 640 + col, lane);
    stH(SM, SLB2, 0, lane, col, lrelu4(c0));
    stH(SM, SLB2, 1, lane, col, lrelu4(c1));
    stH(SM, SLB2, 2, lane, col, lrelu4(c2));
  }
  __syncthreads();
  // R4: goal vals + 3 dots + exps
  f32x4 g0m0, g0m1, g0m2, g1m0, g1m1, g1m2, g2m0, g2m1, g2m2;
  {
    const float vb = aval_b[HD + col];
    g0m0 = binit(vb); g0m1 = g0m0; g0m2 = g0m0;
    g1m0 = g0m0; g1m1 = g0m0; g1m2 = g0m0;
    g2m0 = g0m0; g2m1 = g0m0; g2m2 = g0m0;
    gemmA3s3(g0m0, g0m1, g0m2, g1m0, g1m1, g1m2, g2m0, g2m1, g2m2,
             SM, SLB0, SLB1, SLB2, wsu + OFF_AV1, col, lane);
    if (drow < ROWS){
      int sw5 = (drow & 7) << 5, sw4 = (drow & 7) << 4;
      const unsigned char* kb = SM + ASK + drow * 256;
      short8 kfa = *(const short8*)(kb + (dcb ^ sw5));
      short8 kfb = *(const short8*)(kb + ((dcb + 16) ^ sw5));
      const unsigned char* s0 = SM + SLB0 + drow * 256;
      short8 e0a = *(const short8*)(s0 + (dcb ^ sw4));
      short8 e0b = *(const short8*)(s0 + ((dcb + 16) ^ sw4));
      const unsigned char* s1 = SM + SLB1 + drow * 256;
      short8 e1a = *(const short8*)(s1 + (dcb ^ sw4));
      short8 e1b = *(const short8*)(s1 + ((dcb + 16) ^ sw4));
      const unsigned char* s2 = SM + SLB2 + drow * 256;
      short8 e2a = *(const short8*)(s2 + (dcb ^ sw4));
      short8 e2b = *(const short8*)(s2 + ((dcb + 16) ^ sw4));
      float p0 = dot8(kfa, e0a) + dot8(kfb, e0b);
      float p1 = dot8(kfa, e1a) + dot8(kfb, e1b);
      float p2 = dot8(kfa, e2a) + dot8(kfb, e2b);
      RED8(p0) RED8(p1) RED8(p2)
      if ((lane & 7) == 0){
        float e0 = __expf(p0 * SCALE), e1 = __expf(p1 * SCALE), e2 = __expf(p2 * SCALE);
        eP0[drow] = e0; eP1[drow] = e1; eP2[drow] = e2;
        esm[drow] = (e0 + e1) + e2;
      }
    }
  }
  __syncthreads();
  // R5: ov1 -> SLB0
  {
    f32x4 o;
    #pragma unroll
    for (int r = 0; r < 4; ++r){
      int mr = r0base + r;
      o[r] = ((eP0[mr] * lrelu(g0m0[r]) + eP1[mr] * lrelu(g1m0[r]))
              + eP2[mr] * lrelu(g2m0[r])) / esm[mr];
    }
    stH(SM, SLB0, 0, lane, col, o);
    #pragma unroll
    for (int r = 0; r < 4; ++r){
      int mr = 16 + r0base + r;
      o[r] = ((eP0[mr] * lrelu(g0m1[r]) + eP1[mr] * lrelu(g1m1[r]))
              + eP2[mr] * lrelu(g2m1[r])) / esm[mr];
    }
    stH(SM, SLB0, 1, lane, col, o);
    #pragma unroll
    for (int r = 0; r < 4; ++r){
      int mr = 32 + r0base + r;
      o[r] = ((eP0[mr] * lrelu(g0m2[r]) + eP1[mr] * lrelu(g1m2[r]))
              + eP2[mr] * lrelu(g2m2[r])) / esm[mr];
    }
    stH(SM, SLB0, 2, lane, col, o);
  }
  __syncthreads();
  // R6: merge (hi-B) -> SLB1
  {
    const unsigned short* mh = wsu + OFF_MG(n);
    f32x4 c0 = binit(merge_b[n*HD + col]), c1 = c0, c2 = c0;
    gemmAh_hb3K(c0, c1, c2, SM, AEN,  mh, 384, col, 0,   lane);
    gemmAh_hb3K(c0, c1, c2, SM, AOV,  mh, 384, col, 128, lane);
    gemmAh_hb3K(c0, c1, c2, SM, SLB0, mh, 384, col, 256, lane);
    stH(SM, SLB1, 0, lane, col, lrelu4(c0));
    stH(SM, SLB1, 1, lane, col, lrelu4(c1));
    stH(SM, SLB1, 2, lane, col, lrelu4(c2));
  }
  __syncthreads();
  // R7: coalesced copy SLB1 -> sa_g (padded)
  for (int idx = t; idx < ROWS * 16; idx += 512){
    int row = idx >> 4, ch = idx & 15;
    short8 u = *(const short8*)(SM + SLB1 + row * 256 + ((ch * 16) ^ ((row & 7) << 4)));
    *(short8*)(sa_g + ((size_t)n * PADB + gb0 + row) * HD + ch * 8) = u;
  }
}

// ======================================================================
// PATH A: critic kernel — grid (NBLK, NAG=i), 512 threads, ROWS=48, 52.6KB LDS
// ======================================================================
__global__ __launch_bounds__(512, 4) void critic_kernel(
    const float* __restrict__ s, const float* __restrict__ a,
    const float* __restrict__ senc_b, const float* __restrict__ cval_b,
    const float* __restrict__ cb1, const float* __restrict__ cW2,
    const float* __restrict__ cb2, const unsigned char* __restrict__ wsc,
    const unsigned short* __restrict__ sa_g, float* __restrict__ out)
{
  __shared__ __align__(16) unsigned char SM[52608];
  const int CXN = 0, CEN = 3072, CSMo = 15360, CSA = 27648;
  const int COV = 15360, CH = 27648, CLW = 52224;
  const int t = threadIdx.x, lane = t & 63, wave = t >> 6;
  const int col = wave * 16 + (lane & 15);
  const int i = blockIdx.y;
  const int gb0 = blockIdx.x * ROWS;
  const int j0 = (i == 0) ? 1 : 0;
  const int j1 = (i == 2) ? 1 : 2;
  const float* stats = (const float*)(wsc + WSB_STATS);
  const unsigned short* wsu = (const unsigned short*)(wsc + WSB_W);
  const unsigned short* swh = wsu + OFF_SW(i);
  const f32x4 Z = binit(0.f);
  const int drow = wave * 8 + (lane >> 3);
  const int dcb  = (lane & 7) * 32;
  const int r0base = (lane >> 4) << 2;

  // R0: stage XN_i (hi-only, clamped) + copy sa_j0/j1 -> LDS (hi, swz)
  if (t < ROWS){
    int row = t;
    size_t gb = (size_t)gb0 + row;
    if (gb >= BATCH) gb = BATCH - 1;
    const float* st = stats + i * 40;
    const float* srow = s + ((size_t)i * BATCH + gb) * SD;
    const float* arow = a + ((size_t)i * BATCH + gb) * 2;
    #pragma unroll
    for (int c = 0; c < 32; ++c){
      float v = 0.f;
      if (c < 18) v = (srow[c] - st[c*2]) * st[c*2+1];
      else if (c < 20) v = (arow[c-18] - st[c*2]) * st[c*2+1];
      int off = CXN + row * 64 + ((c * 2) ^ ((row & 3) << 4));
      *(unsigned short*)(SM + off) = f2bf(v);
    }
  }
  for (int idx = t; idx < 2 * ROWS * 16; idx += 512){
    int tile = idx >= ROWS * 16;
    int k = idx - tile * ROWS * 16;
    int row = k >> 4, ch = k & 15;
    int j = tile ? j1 : j0;
    short8 u = *(const short8*)(sa_g + ((size_t)j * PADB + gb0 + row) * HD + ch * 8);
    *(short8*)(SM + CSA + tile * 12288 + row * 256 + ((ch * 16) ^ ((row & 7) << 4))) = u;
  }
  __syncthreads();
  // R1: s_enc -> CEN (hi-A hi-B)
  {
    f32x4 c0 = binit(senc_b[i*HD + col]), c1 = c0, c2 = c0;
    gemmS3_hh(c0, c1, c2, SM, CXN, swh, 768 + col, lane);
    stH(SM, CEN, 0, lane, col, lrelu4(c0));
    stH(SM, CEN, 1, lane, col, lrelu4(c1));
    stH(SM, CEN, 2, lane, col, lrelu4(c2));
  }
  __syncthreads();
  // R2: selsM = s_enc @ M (hi-B) -> CSM (32B-swz)
  {
    f32x4 k0 = Z, k1 = Z, k2 = Z;
    gemmAh_hb3(k0, k1, k2, SM, CEN, wsu + OFF_MT, col, lane);
    stSK(SM, CSMo, 0, lane, col, k0);
    stSK(SM, CSMo, 1, lane, col, k1);
    stSK(SM, CSMo, 2, lane, col, k2);
  }
  __syncthreads();
  // R3: vals GEMMs + dots + 2-way softmax
  f32x4 v00, v01, v02, v10, v11, v12;
  {
    const float vb = cval_b[col];
    v00 = binit(vb); v01 = v00; v02 = v00; v10 = v00; v11 = v00; v12 = v00;
    gemmA2s3(v00, v01, v02, v10, v11, v12, SM, CSA, CSA + 12288,
             wsu + OFF_CV, col, lane);
    if (drow < ROWS){
      int sw5 = (drow & 7) << 5, sw4 = (drow & 7) << 4;
      const unsigned char* mb = SM + CSMo + drow * 256;
      short8 ma = *(const short8*)(mb + (dcb ^ sw5));
      short8 mbf = *(const short8*)(mb + ((dcb + 16) ^ sw5));
      const unsigned char* a0p = SM + CSA + drow * 256;
      short8 a0a = *(const short8*)(a0p + (dcb ^ sw4));
      short8 a0b = *(const short8*)(a0p + ((dcb + 16) ^ sw4));
      const unsigned char* b0p = SM + CSA + 12288 + drow * 256;
      short8 b0a = *(const short8*)(b0p + (dcb ^ sw4));
      short8 b0b = *(const short8*)(b0p + ((dcb + 16) ^ sw4));
      float p0 = dot8(ma, a0a) + dot8(mbf, a0b);
      float p1 = dot8(ma, b0a) + dot8(mbf, b0b);
      RED8(p0) RED8(p1)
      if ((lane & 7) == 0){
        float e0 = __expf(p0 * SCALE), e1 = __expf(p1 * SCALE);
        float inv = 1.f / (e0 + e1);
        ((float*)(SM + CLW))[drow]      = e0 * inv;
        ((float*)(SM + CLW))[48 + drow] = e1 * inv;
      }
    }
  }
  __syncthreads();
  // R4: ov -> COV (hi; overwrites CSM)
  {
    const float* w0 = (const float*)(SM + CLW);
    const float* w1 = w0 + 48;
    f32x4 o;
    #pragma unroll
    for (int r = 0; r < 4; ++r){
      int mr = r0base + r;
      o[r] = w0[mr] * lrelu(v00[r]) + w1[mr] * lrelu(v10[r]);
    }
    stH(SM, COV, 0, lane, col, o);
    #pragma unroll
    for (int r = 0; r < 4; ++r){
      int mr = 16 + r0base + r;
      o[r] = w0[mr] * lrelu(v01[r]) + w1[mr] * lrelu(v11[r]);
    }
    stH(SM, COV, 1, lane, col, o);
    #pragma unroll
    for (int r = 0; r < 4; ++r){
      int mr = 32 + r0base + r;
      o[r] = w0[mr] * lrelu(v02[r]) + w1[mr] * lrelu(v12[r]);
    }
    stH(SM, COV, 2, lane, col, o);
  }
  __syncthreads();
  // R5: h = lrelu([s_enc|ov] @ cW1 + b) -> CH (hi-only; overwrites CSA)
  {
    const unsigned short* c1h = wsu + OFF_C1(i);
    f32x4 h0 = binit(cb1[i*HD + col]), h1 = h0, h2 = h0;
    gemmAh_hb3K(h0, h1, h2, SM, CEN, c1h, 256, col, 0,   lane);
    gemmAh_hb3K(h0, h1, h2, SM, COV, c1h, 256, col, 128, lane);
    stH(SM, CH, 0, lane, col, lrelu4(h0));
    stH(SM, CH, 1, lane, col, lrelu4(h1));
    stH(SM, CH, 2, lane, col, lrelu4(h2));
  }
  __syncthreads();
  // R6: q = h @ cW2 + cb2 (per-row dot, hi-only h), guarded out store
  if (drow < ROWS && gb0 + drow < BATCH){
    int sw4 = (drow & 7) << 4;
    const unsigned char* hb = SM + CH + drow * 256;
    short8 ha = *(const short8*)(hb + (dcb ^ sw4));
    short8 hbf = *(const short8*)(hb + ((dcb + 16) ^ sw4));
    float q0 = 0.f, q1 = 0.f;
    #pragma unroll
    for (int e = 0; e < 8; ++e){
      int d = (lane & 7) * 16 + e;
      float hv = bf2f((unsigned short)ha[e]);
      q0 = fmaf(hv, cW2[(i * HD + d) * 2 + 0], q0);
      q1 = fmaf(hv, cW2[(i * HD + d) * 2 + 1], q1);
    }
    #pragma unroll
    for (int e = 0; e < 8; ++e){
      int d = (lane & 7) * 16 + 8 + e;
      float hv = bf2f((unsigned short)hbf[e]);
      q0 = fmaf(hv, cW2[(i * HD + d) * 2 + 0], q0);
      q1 = fmaf(hv, cW2[(i * HD + d) * 2 + 1], q1);
    }
    RED8(q0) RED8(q1)
    if ((lane & 7) == 0){
      out[((size_t)i * BATCH + gb0 + drow) * 2 + 0] = q0 + cb2[i * 2 + 0];
      out[((size_t)i * BATCH + gb0 + drow) * 2 + 1] = q1 + cb2[i * 2 + 1];
    }
  }
}

// ------------------------------------------------------------ launch -----
extern "C" void kernel_launch(void* const* d_in, const int* in_sizes, int n_in,
                              void* d_out, int out_size, void* d_ws, size_t ws_size,
                              hipStream_t stream) {
  const float* s       = (const float*)d_in[0];
  const float* a       = (const float*)d_in[1];
  const float* en_W    = (const float*)d_in[2];
  const float* en_b    = (const float*)d_in[3];
  const float* oa_W    = (const float*)d_in[4];
  const float* oa_b    = (const float*)d_in[5];
  const float* goal_W  = (const float*)d_in[6];
  const float* goal_b  = (const float*)d_in[7];
  const float* akey_W  = (const float*)d_in[8];
  const float* asel_W  = (const float*)d_in[9];
  const float* aval_W  = (const float*)d_in[10];
  const float* aval_b  = (const float*)d_in[11];
  const float* merge_W = (const float*)d_in[12];
  const float* merge_b = (const float*)d_in[13];
  const float* senc_W  = (const float*)d_in[14];
  const float* senc_b  = (const float*)d_in[15];
  const float* ckey_W  = (const float*)d_in[16];
  const float* csel_W  = (const float*)d_in[17];
  const float* cval_W  = (const float*)d_in[18];
  const float* cval_b  = (const float*)d_in[19];
  const float* cW1     = (const float*)d_in[20];
  const float* cb1     = (const float*)d_in[21];
  const float* cW2     = (const float*)d_in[22];
  const float* cb2     = (const float*)d_in[23];
  unsigned char* wsc = (unsigned char*)d_ws;
  float* F = (float*)(wsc + WSB_F);
  unsigned short* wsu = (unsigned short*)(wsc + WSB_W);
  float* out = (float*)d_out;

  hipMemsetAsync(wsc + WSB_ACCUM, 0, 480, stream);
  stats_partial_kernel<<<384, 256, 0, stream>>>(s, a, (float*)(wsc + WSB_ACCUM));
  fuse_mats_kernel<<<dim3(HD, 4), HD, 0, stream>>>(
      asel_W, akey_W, csel_W, ckey_W, F,
      (const float*)(wsc + WSB_ACCUM), (float*)(wsc + WSB_STATS));
  prep_split_kernel<<<dim3(336, 16), 256, 0, stream>>>(
      F, aval_W, cval_W, merge_W, cW1, cW2, en_W, oa_W, goal_W, senc_W, wsu);

  unsigned short* sa_g = (unsigned short*)(wsc + WSB_SA);
  actor_kernel<<<dim3(NBLK, NAG), 512, 0, stream>>>(
      s, a, en_b, oa_b, goal_b, aval_b, merge_b,
      (const unsigned char*)wsc, sa_g);
  critic_kernel<<<dim3(NBLK, NAG), 512, 0, stream>>>(
      s, a, senc_b, cval_b, cb1, cW2, cb2,
      (const unsigned char*)wsc, (const unsigned short*)sa_g, out);
}

// Round 18
// 178.964 us; speedup vs baseline: 1.2753x; 1.2753x over previous
//
#include <hip/hip_runtime.h>
#include <hip/hip_bf16.h>

#define NAG 3
#define BATCH 32768
#define HD 128
#define SD 18
#define ROWS 48
#define NBLK 683
#define PADB (NBLK * ROWS)     // 32784
#define EPSV 1e-5f
#define SCALE 0.08838834764831845f

typedef __attribute__((ext_vector_type(8))) short short8;
typedef __attribute__((ext_vector_type(4))) float f32x4;

// ---------------- ws byte layout ----------------
#define WSB_STATS 0
#define WSB_F     1024
#define WSB_W     197632
#define OFF_FT0 0
#define OFF_FT1 32768
#define OFF_MT  65536
#define OFF_AV0 98304
#define OFF_AV1 131072
#define OFF_CV  163840
#define OFF_MG(n) (196608 + (n)*98304)
#define OFF_C1(n) (491520 + (n)*65536)
#define OFF_C2(n) (688128 + (n)*4096)
#define OFF_SW(n) (700416 + (n)*57344)
#define WSB_SA  2097152
// stats partials time-share the first 61.4KB of the sa_g region:
// written by stats_partial_kernel, consumed by fuse_mats_kernel, then
// overwritten by actor_kernel's sa_g stores (stream-ordered).
#define SA_BYTES_P ((size_t)NAG * PADB * HD * 2)

__device__ __forceinline__ float lrelu(float x){ return x >= 0.0f ? x : 0.01f * x; }
__device__ __forceinline__ f32x4 lrelu4(f32x4 v){
  f32x4 r; r[0]=lrelu(v[0]); r[1]=lrelu(v[1]); r[2]=lrelu(v[2]); r[3]=lrelu(v[3]); return r;
}
__device__ __forceinline__ f32x4 binit(float b){ f32x4 c; c[0]=b;c[1]=b;c[2]=b;c[3]=b; return c; }
__device__ __forceinline__ unsigned short f2bf(float f){
  __hip_bfloat16 h = __float2bfloat16(f);     // HW v_cvt (RNE)
  return *reinterpret_cast<unsigned short*>(&h);
}
__device__ __forceinline__ float bf2f(unsigned short h){
  return __uint_as_float(((unsigned int)h) << 16);
}

// ---------------- prep: batch stats (384 blocks, atomic-free partials) ----------------
__global__ void stats_partial_kernel(const float* __restrict__ s,
                                     const float* __restrict__ a,
                                     float* __restrict__ partial){
  const int n = blockIdx.x >> 7;        // 3 agents x 128 chunks
  const int chunk = blockIdx.x & 127;
  const int t = threadIdx.x, lane = t & 63, wave = t >> 6;
  const int rows = BATCH / 128;         // 256 rows, 1 per thread
  const int b0 = chunk * rows;
  float sum[20], sq[20];
  #pragma unroll
  for (int c = 0; c < 20; ++c){ sum[c] = 0.f; sq[c] = 0.f; }
  {
    int b = b0 + t;
    const float* row = s + ((size_t)n * BATCH + b) * SD;
    #pragma unroll
    for (int c = 0; c < SD; ++c){ float v = row[c]; sum[c] += v; sq[c] += v * v; }
    const float* ra = a + ((size_t)n * BATCH + b) * 2;
    #pragma unroll
    for (int c = 0; c < 2; ++c){ float v = ra[c]; sum[SD + c] += v; sq[SD + c] += v * v; }
  }
  // wave butterfly reduce (no barriers)
  #pragma unroll
  for (int c = 0; c < 20; ++c){
    #pragma unroll
    for (int off = 1; off < 64; off <<= 1){
      sum[c] += __shfl_xor(sum[c], off);
      sq[c]  += __shfl_xor(sq[c],  off);
    }
  }
  __shared__ float red[4][40];
  if (lane == 0){
    #pragma unroll
    for (int c = 0; c < 20; ++c){ red[wave][c*2] = sum[c]; red[wave][c*2+1] = sq[c]; }
  }
  __syncthreads();
  if (t < 40){
    float v = red[0][t] + red[1][t] + red[2][t] + red[3][t];
    partial[((size_t)(n * 128 + chunk)) * 40 + t] = v;
  }
}

// ---------------- prep: F_m = sel @ key^T + stats finalize ----------------
__global__ void fuse_mats_kernel(const float* __restrict__ asel, const float* __restrict__ akey,
                                 const float* __restrict__ csel, const float* __restrict__ ckey,
                                 float* __restrict__ F, const float* __restrict__ partial,
                                 float* __restrict__ stats){
  const int m  = blockIdx.y;
  if (m == 3){
    if (blockIdx.x == 0){
      int i = threadIdx.x;
      if (i < 60){
        int n = i / 20, c = i % 20;
        float S = 0.f, SQ = 0.f;
        const float* p = partial + (size_t)n * 128 * 40 + c * 2;
        #pragma unroll 4
        for (int ch = 0; ch < 128; ++ch){
          S  += p[(size_t)ch * 40 + 0];
          SQ += p[(size_t)ch * 40 + 1];
        }
        float mean = S / (float)BATCH;
        float var = SQ / (float)BATCH - mean * mean;
        stats[i * 2 + 0] = mean;
        stats[i * 2 + 1] = 1.0f / sqrtf(var + EPSV);
      }
    }
    return;
  }
  const int h1 = blockIdx.x;
  const int h2 = threadIdx.x;
  const float* A; const float* Bm;
  if (m == 0){ A = asel;            Bm = akey; }
  else if (m == 1){ A = asel + HD*HD; Bm = akey + HD*HD; }
  else { A = csel; Bm = ckey; }
  const float* arow = A + h1 * HD;
  const float* brow = Bm + h2 * HD;
  float acc = 0.f;
  #pragma unroll 4
  for (int d = 0; d < HD; ++d) acc = fmaf(arow[d], brow[d], acc);
  F[m * HD * HD + h1 * HD + h2] = acc;
}

// ---------------- prep: all weight splits + smallpack ----------------
__global__ void prep_split_kernel(const float* __restrict__ F, const float* __restrict__ aval_W,
                                  const float* __restrict__ cval_W, const float* __restrict__ merge_W,
                                  const float* __restrict__ cW1, const float* __restrict__ cW2,
                                  const float* __restrict__ en_W, const float* __restrict__ oa_W,
                                  const float* __restrict__ goal_W, const float* __restrict__ senc_W,
                                  unsigned short* __restrict__ wsu){
  const int job = blockIdx.y;
  const int idx = blockIdx.x * 256 + threadIdx.x;
  if (job == 15){
    if (idx >= 3 * 896 * 32) return;
    int k = idx & 31; int c = (idx >> 5) % 896; int n = idx / (896 * 32);
    int tt = c >> 7, cc = c & 127;
    float v = 0.f;
    if (tt == 0){
      if (k < 4) v = en_W[(size_t)(n*6 + k)*128 + cc];
      else if (k == 18 || k == 19) v = en_W[(size_t)(n*6 + 4 + (k-18))*128 + cc];
    } else if (tt <= 2){
      int j = tt - 1; int kk = k - (4 + 4*j);
      if (kk >= 0 && kk < 4) v = oa_W[(size_t)(n*4 + kk)*128 + cc];
    } else if (tt <= 5){
      int j = tt - 3; int kk = k - (12 + 2*j);
      if (kk >= 0 && kk < 2) v = goal_W[(size_t)(n*2 + kk)*128 + cc];
    } else {
      if (k < 18) v = senc_W[(size_t)(n*18 + k)*128 + cc];
    }
    unsigned short hi = f2bf(v); float lo = v - bf2f(hi);
    unsigned short* dh = wsu + OFF_SW(n);
    dh[c * 32 + k] = hi;
    dh[28672 + c * 32 + k] = f2bf(lo);
    return;
  }
  const float* src; unsigned short* dh; int K = 128, Csrc = 128, Cdst = 128, loff = 16384;
  switch (job){
    case 0: src = F;              dh = wsu + OFF_FT0; break;
    case 1: src = F + 16384;      dh = wsu + OFF_FT1; break;
    case 2: src = F + 32768;      dh = wsu + OFF_MT;  break;
    case 3: src = aval_W;         dh = wsu + OFF_AV0; break;
    case 4: src = aval_W + 16384; dh = wsu + OFF_AV1; break;
    case 5: src = cval_W;         dh = wsu + OFF_CV;  break;
    case 6: case 7: case 8: {
      int n = job - 6; src = merge_W + (size_t)n * 49152; dh = wsu + OFF_MG(n);
      K = 384; loff = 49152; } break;
    case 9: case 10: case 11: {
      int n = job - 9; src = cW1 + (size_t)n * 32768; dh = wsu + OFF_C1(n);
      K = 256; loff = 32768; } break;
    default: {
      int n = job - 12; src = cW2 + (size_t)n * 256; dh = wsu + OFF_C2(n);
      Csrc = 2; Cdst = 16; loff = 2048; } break;
  }
  if (idx >= K * Cdst) return;
  int k = idx / Cdst, c = idx - k * Cdst;
  float v = (c < Csrc) ? src[(size_t)k * Csrc + c] : 0.f;
  unsigned short hi = f2bf(v);
  dh[(size_t)c * K + k] = hi;
  dh[loff + (size_t)c * K + k] = f2bf(v - bf2f(hi));
}

// ---------------- MFMA helpers ----------------
__device__ __forceinline__ short8 ldAh(const unsigned char* sm, int base, int mi, int ks, int lane){
  int row = mi * 16 + (lane & 15);
  int bc  = ks * 64 + ((lane >> 4) << 4);
  return *(const short8*)(sm + base + row * 256 + (bc ^ ((row & 7) << 4)));
}
__device__ __forceinline__ short8 ldA32h(const unsigned char* sm, int base, int mi, int lane){
  int row = mi * 16 + (lane & 15);
  int bc  = (lane >> 4) << 4;
  return *(const short8*)(sm + base + row * 64 + (bc ^ ((row & 3) << 4)));
}

#define MM1(acc, ah, bh) \
  acc = __builtin_amdgcn_mfma_f32_16x16x32_bf16(ah, bh, acc, 0, 0, 0);

// hi-A, hi-B small encoder: 1 MFMA/mt
__device__ __forceinline__ void gemmS3_hh(f32x4& c0, f32x4& c1, f32x4& c2,
                                          const unsigned char* sm, int abase,
                                          const unsigned short* wh, int bcol, int lane){
  const size_t bb = (size_t)bcol * 32 + ((lane >> 4) << 3);
  const short8 bh = *(const short8*)(wh + bb);
  MM1(c0, ldA32h(sm, abase, 0, lane), bh);
  MM1(c1, ldA32h(sm, abase, 1, lane), bh);
  MM1(c2, ldA32h(sm, abase, 2, lane), bh);
}
__device__ __forceinline__ void gemmAW2_3(f32x4& k0, f32x4& k1, f32x4& k2,
                                          f32x4& m0, f32x4& m1, f32x4& m2,
                                          const unsigned char* sm, int abase,
                                          const unsigned short* wh0, const unsigned short* wh1,
                                          int bcol, int lane){
  const size_t bb = (size_t)bcol * 128 + ((lane >> 4) << 3);
  #pragma unroll
  for (int ks = 0; ks < 4; ++ks){
    short8 a0 = ldAh(sm, abase, 0, ks, lane);
    short8 a1 = ldAh(sm, abase, 1, ks, lane);
    short8 a2 = ldAh(sm, abase, 2, ks, lane);
    const short8 b0 = *(const short8*)(wh0 + bb + ks * 32);
    const short8 b1 = *(const short8*)(wh1 + bb + ks * 32);
    MM1(k0, a0, b0); MM1(k1, a1, b0); MM1(k2, a2, b0);
    MM1(m0, a0, b1); MM1(m1, a1, b1); MM1(m2, a2, b1);
  }
}
__device__ __forceinline__ void gemmA2s3(f32x4& c0, f32x4& c1, f32x4& c2,
                                         f32x4& d0, f32x4& d1, f32x4& d2,
                                         const unsigned char* sm, int a0b, int a1b,
                                         const unsigned short* wh, int bcol, int lane){
  const size_t bb = (size_t)bcol * 128 + ((lane >> 4) << 3);
  #pragma unroll
  for (int ks = 0; ks < 4; ++ks){
    const short8 bh = *(const short8*)(wh + bb + ks * 32);
    short8 x;
    x = ldAh(sm, a0b, 0, ks, lane); MM1(c0, x, bh);
    x = ldAh(sm, a0b, 1, ks, lane); MM1(c1, x, bh);
    x = ldAh(sm, a0b, 2, ks, lane); MM1(c2, x, bh);
    x = ldAh(sm, a1b, 0, ks, lane); MM1(d0, x, bh);
    x = ldAh(sm, a1b, 1, ks, lane); MM1(d1, x, bh);
    x = ldAh(sm, a1b, 2, ks, lane); MM1(d2, x, bh);
  }
}
__device__ __forceinline__ void gemmA3s3(f32x4& c0, f32x4& c1, f32x4& c2,
                                         f32x4& d0, f32x4& d1, f32x4& d2,
                                         f32x4& e0, f32x4& e1, f32x4& e2,
                                         const unsigned char* sm, int a0b, int a1b, int a2b,
                                         const unsigned short* wh, int bcol, int lane){
  const size_t bb = (size_t)bcol * 128 + ((lane >> 4) << 3);
  #pragma unroll
  for (int ks = 0; ks < 4; ++ks){
    const short8 bh = *(const short8*)(wh + bb + ks * 32);
    short8 x;
    x = ldAh(sm, a0b, 0, ks, lane); MM1(c0, x, bh);
    x = ldAh(sm, a0b, 1, ks, lane); MM1(c1, x, bh);
    x = ldAh(sm, a0b, 2, ks, lane); MM1(c2, x, bh);
    x = ldAh(sm, a1b, 0, ks, lane); MM1(d0, x, bh);
    x = ldAh(sm, a1b, 1, ks, lane); MM1(d1, x, bh);
    x = ldAh(sm, a1b, 2, ks, lane); MM1(d2, x, bh);
    x = ldAh(sm, a2b, 0, ks, lane); MM1(e0, x, bh);
    x = ldAh(sm, a2b, 1, ks, lane); MM1(e1, x, bh);
    x = ldAh(sm, a2b, 2, ks, lane); MM1(e2, x, bh);
  }
}
__device__ __forceinline__ void gemmAh_hb3K(f32x4& c0, f32x4& c1, f32x4& c2,
                                            const unsigned char* sm, int abase,
                                            const unsigned short* wh,
                                            int K, int bcol, int kBase, int lane){
  const size_t bb = (size_t)bcol * K + kBase + ((lane >> 4) << 3);
  #pragma unroll
  for (int ks = 0; ks < 4; ++ks){
    const short8 bh = *(const short8*)(wh + bb + ks * 32);
    short8 a;
    a = ldAh(sm, abase, 0, ks, lane); MM1(c0, a, bh);
    a = ldAh(sm, abase, 1, ks, lane); MM1(c1, a, bh);
    a = ldAh(sm, abase, 2, ks, lane); MM1(c2, a, bh);
  }
}
__device__ __forceinline__ void gemmAh_hb3(f32x4& c0, f32x4& c1, f32x4& c2,
                                           const unsigned char* sm, int abase,
                                           const unsigned short* wh, int bcol, int lane){
  const size_t bb = (size_t)bcol * 128 + ((lane >> 4) << 3);
  #pragma unroll
  for (int ks = 0; ks < 4; ++ks){
    const short8 bh = *(const short8*)(wh + bb + ks * 32);
    short8 a;
    a = ldAh(sm, abase, 0, ks, lane); MM1(c0, a, bh);
    a = ldAh(sm, abase, 1, ks, lane); MM1(c1, a, bh);
    a = ldAh(sm, abase, 2, ks, lane); MM1(c2, a, bh);
  }
}

// stores
__device__ __forceinline__ void stH(unsigned char* sm, int base, int mi, int lane, int col, f32x4 v){
  #pragma unroll
  for (int r = 0; r < 4; ++r){
    int row = mi * 16 + ((lane >> 4) << 2) + r;
    int off = base + row * 256 + ((col * 2) ^ ((row & 7) << 4));
    *(unsigned short*)(sm + off) = f2bf(v[r]);
  }
}
__device__ __forceinline__ void stSK(unsigned char* sm, int base, int mi, int lane, int col, f32x4 v){
  #pragma unroll
  for (int r = 0; r < 4; ++r){
    int row = mi * 16 + ((lane >> 4) << 2) + r;
    int off = base + row * 256 + ((col * 2) ^ ((row & 7) << 5));
    *(unsigned short*)(sm + off) = f2bf(v[r]);
  }
}
__device__ __forceinline__ float dot8(short8 x, short8 y){
  float acc = 0.f;
  #pragma unroll
  for (int e = 0; e < 8; ++e)
    acc = fmaf(bf2f((unsigned short)x[e]), bf2f((unsigned short)y[e]), acc);
  return acc;
}
#define RED8(p) { p += __shfl_xor(p, 1); p += __shfl_xor(p, 2); p += __shfl_xor(p, 4); }

// ======================================================================
// PATH A: actor kernel — grid (NBLK, NAG), 512 threads, ROWS=48, 77.6KB LDS
// (XN hi-only)
// ======================================================================
__global__ __launch_bounds__(512, 4) void actor_kernel(
    const float* __restrict__ s, const float* __restrict__ a,
    const float* __restrict__ en_b, const float* __restrict__ oa_b,
    const float* __restrict__ goal_b, const float* __restrict__ aval_b,
    const float* __restrict__ merge_b, const unsigned char* __restrict__ wsc,
    unsigned short* __restrict__ sa_g)
{
  __shared__ __align__(16) unsigned char SM[77568];
  const int AXN = 0, AEN = 3072, AOV = 15360, ASK = 27648;
  const int SLB0 = 39936, SLB1 = 52224, SLB2 = 64512, AEP = 76800;
  const int t = threadIdx.x, lane = t & 63, wave = t >> 6;
  const int col = wave * 16 + (lane & 15);
  const int n = blockIdx.y;
  const int gb0 = blockIdx.x * ROWS;
  const float* stats = (const float*)(wsc + WSB_STATS);
  const unsigned short* wsu = (const unsigned short*)(wsc + WSB_W);
  const unsigned short* swh = wsu + OFF_SW(n);
  float* eP0 = (float*)(SM + AEP);
  float* eP1 = eP0 + 48;
  float* eP2 = eP0 + 96;
  float* esm = eP0 + 144;
  const f32x4 Z = binit(0.f);
  const int drow = wave * 8 + (lane >> 3);
  const int dcb  = (lane & 7) * 32;
  const int r0base = (lane >> 4) << 2;

  // init: stage normalized XN (hi-only, K=32), clamped reads
  if (t < ROWS){
    int row = t;
    size_t gb = (size_t)gb0 + row;
    if (gb >= BATCH) gb = BATCH - 1;
    const float* st = stats + n * 40;
    const float* srow = s + ((size_t)n * BATCH + gb) * SD;
    const float* arow = a + ((size_t)n * BATCH + gb) * 2;
    #pragma unroll
    for (int c = 0; c < 32; ++c){
      float v = 0.f;
      if (c < 18) v = (srow[c] - st[c*2]) * st[c*2+1];
      else if (c < 20) v = (arow[c-18] - st[c*2]) * st[c*2+1];
      int off = AXN + row * 64 + ((c * 2) ^ ((row & 3) << 4));
      *(unsigned short*)(SM + off) = f2bf(v);
    }
  }
  __syncthreads();
  // R0: en_enc -> AEN ; oa slices -> SLB0, SLB1 (hi-A hi-B)
  {
    f32x4 c0 = binit(en_b[n*HD + col]), c1 = c0, c2 = c0;
    gemmS3_hh(c0, c1, c2, SM, AXN, swh, col, lane);
    stH(SM, AEN, 0, lane, col, lrelu4(c0));
    stH(SM, AEN, 1, lane, col, lrelu4(c1));
    stH(SM, AEN, 2, lane, col, lrelu4(c2));
    const float bb = oa_b[n*HD + col];
    c0 = binit(bb); c1 = c0; c2 = c0;
    gemmS3_hh(c0, c1, c2, SM, AXN, swh, 128 + col, lane);
    stH(SM, SLB0, 0, lane, col, lrelu4(c0));
    stH(SM, SLB0, 1, lane, col, lrelu4(c1));
    stH(SM, SLB0, 2, lane, col, lrelu4(c2));
    c0 = binit(bb); c1 = c0; c2 = c0;
    gemmS3_hh(c0, c1, c2, SM, AXN, swh, 256 + col, lane);
    stH(SM, SLB1, 0, lane, col, lrelu4(c0));
    stH(SM, SLB1, 1, lane, col, lrelu4(c1));
    stH(SM, SLB1, 2, lane, col, lrelu4(c2));
  }
  __syncthreads();
  // R1: selk0 -> AOV, selk1 -> ASK (hi-B)
  {
    f32x4 k0 = Z, k1 = Z, k2 = Z, m0 = Z, m1 = Z, m2 = Z;
    gemmAW2_3(k0, k1, k2, m0, m1, m2, SM, AEN,
              wsu + OFF_FT0, wsu + OFF_FT1, col, lane);
    stSK(SM, AOV, 0, lane, col, k0); stSK(SM, AOV, 1, lane, col, k1); stSK(SM, AOV, 2, lane, col, k2);
    stSK(SM, ASK, 0, lane, col, m0); stSK(SM, ASK, 1, lane, col, m1); stSK(SM, ASK, 2, lane, col, m2);
  }
  __syncthreads();
  // R2: oa vals + logit dots + exp
  f32x4 va0, va1, va2, vb0, vb1, vb2;
  {
    const float vb = aval_b[col];
    va0 = binit(vb); va1 = va0; va2 = va0; vb0 = va0; vb1 = va0; vb2 = va0;
    gemmA2s3(va0, va1, va2, vb0, vb1, vb2, SM, SLB0, SLB1, wsu + OFF_AV0, col, lane);
    if (drow < ROWS){
      int sw5 = (drow & 7) << 5, sw4 = (drow & 7) << 4;
      const unsigned char* kb = SM + AOV + drow * 256;
      short8 kfa = *(const short8*)(kb + (dcb ^ sw5));
      short8 kfb = *(const short8*)(kb + ((dcb + 16) ^ sw5));
      const unsigned char* s0 = SM + SLB0 + drow * 256;
      short8 e0a = *(const short8*)(s0 + (dcb ^ sw4));
      short8 e0b = *(const short8*)(s0 + ((dcb + 16) ^ sw4));
      const unsigned char* s1 = SM + SLB1 + drow * 256;
      short8 e1a = *(const short8*)(s1 + (dcb ^ sw4));
      short8 e1b = *(const short8*)(s1 + ((dcb + 16) ^ sw4));
      float p0 = dot8(kfa, e0a) + dot8(kfb, e0b);
      float p1 = dot8(kfa, e1a) + dot8(kfb, e1b);
      RED8(p0) RED8(p1)
      if ((lane & 7) == 0){
        float e0 = __expf(p0 * SCALE), e1 = __expf(p1 * SCALE);
        eP0[drow] = e0; eP1[drow] = e1; esm[drow] = e0 + e1;
      }
    }
  }
  __syncthreads();
  // R3: ov0 -> AOV ; goal slices g0,g1,g2 -> SLB0,1,2 (hi-A hi-B)
  {
    f32x4 o;
    #pragma unroll
    for (int r = 0; r < 4; ++r){
      int mr = r0base + r;
      o[r] = (eP0[mr] * lrelu(va0[r]) + eP1[mr] * lrelu(vb0[r])) / esm[mr];
    }
    stH(SM, AOV, 0, lane, col, o);
    #pragma unroll
    for (int r = 0; r < 4; ++r){
      int mr = 16 + r0base + r;
      o[r] = (eP0[mr] * lrelu(va1[r]) + eP1[mr] * lrelu(vb1[r])) / esm[mr];
    }
    stH(SM, AOV, 1, lane, col, o);
    #pragma unroll
    for (int r = 0; r < 4; ++r){
      int mr = 32 + r0base + r;
      o[r] = (eP0[mr] * lrelu(va2[r]) + eP1[mr] * lrelu(vb2[r])) / esm[mr];
    }
    stH(SM, AOV, 2, lane, col, o);
    const float bb = goal_b[n*HD + col];
    f32x4 c0 = binit(bb), c1 = c0, c2 = c0;
    gemmS3_hh(c0, c1, c2, SM, AXN, swh, 384 + col, lane);
    stH(SM, SLB0, 0, lane, col, lrelu4(c0));
    stH(SM, SLB0, 1, lane, col, lrelu4(c1));
    stH(SM, SLB0, 2, lane, col, lrelu4(c2));
    c0 = binit(bb); c1 = c0; c2 = c0;
    gemmS3_hh(c0, c1, c2, SM, AXN, swh, 512 + col, lane);
    stH(SM, SLB1, 0, lane, col, lrelu4(c0));
    stH(SM, SLB1, 1, lane, col, lrelu4(c1));
    stH(SM, SLB1, 2, lane, col, lrelu4(c2));
    c0 = binit(bb); c1 = c0; c2 = c0;
    gemmS3_hh(c0, c1, c2, SM, AXN, swh, 640 + col, lane);
    stH(SM, SLB2, 0, lane, col, lrelu4(c0));
    stH(SM, SLB2, 1, lane, col, lrelu4(c1));
    stH(SM, SLB2, 2, lane, col, lrelu4(c2));
  }
  __syncthreads();
  // R4: goal vals + 3 dots + exps
  f32x4 g0m0, g0m1, g0m2, g1m0, g1m1, g1m2, g2m0, g2m1, g2m2;
  {
    const float vb = aval_b[HD + col];
    g0m0 = binit(vb); g0m1 = g0m0; g0m2 = g0m0;
    g1m0 = g0m0; g1m1 = g0m0; g1m2 = g0m0;
    g2m0 = g0m0; g2m1 = g0m0; g2m2 = g0m0;
    gemmA3s3(g0m0, g0m1, g0m2, g1m0, g1m1, g1m2, g2m0, g2m1, g2m2,
             SM, SLB0, SLB1, SLB2, wsu + OFF_AV1, col, lane);
    if (drow < ROWS){
      int sw5 = (drow & 7) << 5, sw4 = (drow & 7) << 4;
      const unsigned char* kb = SM + ASK + drow * 256;
      short8 kfa = *(const short8*)(kb + (dcb ^ sw5));
      short8 kfb = *(const short8*)(kb + ((dcb + 16) ^ sw5));
      const unsigned char* s0 = SM + SLB0 + drow * 256;
      short8 e0a = *(const short8*)(s0 + (dcb ^ sw4));
      short8 e0b = *(const short8*)(s0 + ((dcb + 16) ^ sw4));
      const unsigned char* s1 = SM + SLB1 + drow * 256;
      short8 e1a = *(const short8*)(s1 + (dcb ^ sw4));
      short8 e1b = *(const short8*)(s1 + ((dcb + 16) ^ sw4));
      const unsigned char* s2 = SM + SLB2 + drow * 256;
      short8 e2a = *(const short8*)(s2 + (dcb ^ sw4));
      short8 e2b = *(const short8*)(s2 + ((dcb + 16) ^ sw4));
      float p0 = dot8(kfa, e0a) + dot8(kfb, e0b);
      float p1 = dot8(kfa, e1a) + dot8(kfb, e1b);
      float p2 = dot8(kfa, e2a) + dot8(kfb, e2b);
      RED8(p0) RED8(p1) RED8(p2)
      if ((lane & 7) == 0){
        float e0 = __expf(p0 * SCALE), e1 = __expf(p1 * SCALE), e2 = __expf(p2 * SCALE);
        eP0[drow] = e0; eP1[drow] = e1; eP2[drow] = e2;
        esm[drow] = (e0 + e1) + e2;
      }
    }
  }
  __syncthreads();
  // R5: ov1 -> SLB0
  {
    f32x4 o;
    #pragma unroll
    for (int r = 0; r < 4; ++r){
      int mr = r0base + r;
      o[r] = ((eP0[mr] * lrelu(g0m0[r]) + eP1[mr] * lrelu(g1m0[r]))
              + eP2[mr] * lrelu(g2m0[r])) / esm[mr];
    }
    stH(SM, SLB0, 0, lane, col, o);
    #pragma unroll
    for (int r = 0; r < 4; ++r){
      int mr = 16 + r0base + r;
      o[r] = ((eP0[mr] * lrelu(g0m1[r]) + eP1[mr] * lrelu(g1m1[r]))
              + eP2[mr] * lrelu(g2m1[r])) / esm[mr];
    }
    stH(SM, SLB0, 1, lane, col, o);
    #pragma unroll
    for (int r = 0; r < 4; ++r){
      int mr = 32 + r0base + r;
      o[r] = ((eP0[mr] * lrelu(g0m2[r]) + eP1[mr] * lrelu(g1m2[r]))
              + eP2[mr] * lrelu(g2m2[r])) / esm[mr];
    }
    stH(SM, SLB0, 2, lane, col, o);
  }
  __syncthreads();
  // R6: merge (hi-B) -> SLB1
  {
    const unsigned short* mh = wsu + OFF_MG(n);
    f32x4 c0 = binit(merge_b[n*HD + col]), c1 = c0, c2 = c0;
    gemmAh_hb3K(c0, c1, c2, SM, AEN,  mh, 384, col, 0,   lane);
    gemmAh_hb3K(c0, c1, c2, SM, AOV,  mh, 384, col, 128, lane);
    gemmAh_hb3K(c0, c1, c2, SM, SLB0, mh, 384, col, 256, lane);
    stH(SM, SLB1, 0, lane, col, lrelu4(c0));
    stH(SM, SLB1, 1, lane, col, lrelu4(c1));
    stH(SM, SLB1, 2, lane, col, lrelu4(c2));
  }
  __syncthreads();
  // R7: coalesced copy SLB1 -> sa_g (padded)
  for (int idx = t; idx < ROWS * 16; idx += 512){
    int row = idx >> 4, ch = idx & 15;
    short8 u = *(const short8*)(SM + SLB1 + row * 256 + ((ch * 16) ^ ((row & 7) << 4)));
    *(short8*)(sa_g + ((size_t)n * PADB + gb0 + row) * HD + ch * 8) = u;
  }
}

// ======================================================================
// PATH A: critic kernel — grid (NBLK, NAG=i), 512 threads, ROWS=48, 52.6KB LDS
// ======================================================================
__global__ __launch_bounds__(512, 4) void critic_kernel(
    const float* __restrict__ s, const float* __restrict__ a,
    const float* __restrict__ senc_b, const float* __restrict__ cval_b,
    const float* __restrict__ cb1, const float* __restrict__ cW2,
    const float* __restrict__ cb2, const unsigned char* __restrict__ wsc,
    const unsigned short* __restrict__ sa_g, float* __restrict__ out)
{
  __shared__ __align__(16) unsigned char SM[52608];
  const int CXN = 0, CEN = 3072, CSMo = 15360, CSA = 27648;
  const int COV = 15360, CH = 27648, CLW = 52224;
  const int t = threadIdx.x, lane = t & 63, wave = t >> 6;
  const int col = wave * 16 + (lane & 15);
  const int i = blockIdx.y;
  const int gb0 = blockIdx.x * ROWS;
  const int j0 = (i == 0) ? 1 : 0;
  const int j1 = (i == 2) ? 1 : 2;
  const float* stats = (const float*)(wsc + WSB_STATS);
  const unsigned short* wsu = (const unsigned short*)(wsc + WSB_W);
  const unsigned short* swh = wsu + OFF_SW(i);
  const f32x4 Z = binit(0.f);
  const int drow = wave * 8 + (lane >> 3);
  const int dcb  = (lane & 7) * 32;
  const int r0base = (lane >> 4) << 2;

  // R0: stage XN_i (hi-only, clamped) + copy sa_j0/j1 -> LDS (hi, swz)
  if (t < ROWS){
    int row = t;
    size_t gb = (size_t)gb0 + row;
    if (gb >= BATCH) gb = BATCH - 1;
    const float* st = stats + i * 40;
    const float* srow = s + ((size_t)i * BATCH + gb) * SD;
    const float* arow = a + ((size_t)i * BATCH + gb) * 2;
    #pragma unroll
    for (int c = 0; c < 32; ++c){
      float v = 0.f;
      if (c < 18) v = (srow[c] - st[c*2]) * st[c*2+1];
      else if (c < 20) v = (arow[c-18] - st[c*2]) * st[c*2+1];
      int off = CXN + row * 64 + ((c * 2) ^ ((row & 3) << 4));
      *(unsigned short*)(SM + off) = f2bf(v);
    }
  }
  for (int idx = t; idx < 2 * ROWS * 16; idx += 512){
    int tile = idx >= ROWS * 16;
    int k = idx - tile * ROWS * 16;
    int row = k >> 4, ch = k & 15;
    int j = tile ? j1 : j0;
    short8 u = *(const short8*)(sa_g + ((size_t)j * PADB + gb0 + row) * HD + ch * 8);
    *(short8*)(SM + CSA + tile * 12288 + row * 256 + ((ch * 16) ^ ((row & 7) << 4))) = u;
  }
  __syncthreads();
  // R1: s_enc -> CEN (hi-A hi-B)
  {
    f32x4 c0 = binit(senc_b[i*HD + col]), c1 = c0, c2 = c0;
    gemmS3_hh(c0, c1, c2, SM, CXN, swh, 768 + col, lane);
    stH(SM, CEN, 0, lane, col, lrelu4(c0));
    stH(SM, CEN, 1, lane, col, lrelu4(c1));
    stH(SM, CEN, 2, lane, col, lrelu4(c2));
  }
  __syncthreads();
  // R2: selsM = s_enc @ M (hi-B) -> CSM (32B-swz)
  {
    f32x4 k0 = Z, k1 = Z, k2 = Z;
    gemmAh_hb3(k0, k1, k2, SM, CEN, wsu + OFF_MT, col, lane);
    stSK(SM, CSMo, 0, lane, col, k0);
    stSK(SM, CSMo, 1, lane, col, k1);
    stSK(SM, CSMo, 2, lane, col, k2);
  }
  __syncthreads();
  // R3: vals GEMMs + dots + 2-way softmax
  f32x4 v00, v01, v02, v10, v11, v12;
  {
    const float vb = cval_b[col];
    v00 = binit(vb); v01 = v00; v02 = v00; v10 = v00; v11 = v00; v12 = v00;
    gemmA2s3(v00, v01, v02, v10, v11, v12, SM, CSA, CSA + 12288,
             wsu + OFF_CV, col, lane);
    if (drow < ROWS){
      int sw5 = (drow & 7) << 5, sw4 = (drow & 7) << 4;
      const unsigned char* mb = SM + CSMo + drow * 256;
      short8 ma = *(const short8*)(mb + (dcb ^ sw5));
      short8 mbf = *(const short8*)(mb + ((dcb + 16) ^ sw5));
      const unsigned char* a0p = SM + CSA + drow * 256;
      short8 a0a = *(const short8*)(a0p + (dcb ^ sw4));
      short8 a0b = *(const short8*)(a0p + ((dcb + 16) ^ sw4));
      const unsigned char* b0p = SM + CSA + 12288 + drow * 256;
      short8 b0a = *(const short8*)(b0p + (dcb ^ sw4));
      short8 b0b = *(const short8*)(b0p + ((dcb + 16) ^ sw4));
      float p0 = dot8(ma, a0a) + dot8(mbf, a0b);
      float p1 = dot8(ma, b0a) + dot8(mbf, b0b);
      RED8(p0) RED8(p1)
      if ((lane & 7) == 0){
        float e0 = __expf(p0 * SCALE), e1 = __expf(p1 * SCALE);
        float inv = 1.f / (e0 + e1);
        ((float*)(SM + CLW))[drow]      = e0 * inv;
        ((float*)(SM + CLW))[48 + drow] = e1 * inv;
      }
    }
  }
  __syncthreads();
  // R4: ov -> COV (hi; overwrites CSM)
  {
    const float* w0 = (const float*)(SM + CLW);
    const float* w1 = w0 + 48;
    f32x4 o;
    #pragma unroll
    for (int r = 0; r < 4; ++r){
      int mr = r0base + r;
      o[r] = w0[mr] * lrelu(v00[r]) + w1[mr] * lrelu(v10[r]);
    }
    stH(SM, COV, 0, lane, col, o);
    #pragma unroll
    for (int r = 0; r < 4; ++r){
      int mr = 16 + r0base + r;
      o[r] = w0[mr] * lrelu(v01[r]) + w1[mr] * lrelu(v11[r]);
    }
    stH(SM, COV, 1, lane, col, o);
    #pragma unroll
    for (int r = 0; r < 4; ++r){
      int mr = 32 + r0base + r;
      o[r] = w0[mr] * lrelu(v02[r]) + w1[mr] * lrelu(v12[r]);
    }
    stH(SM, COV, 2, lane, col, o);
  }
  __syncthreads();
  // R5: h = lrelu([s_enc|ov] @ cW1 + b) -> CH (hi-only; overwrites CSA)
  {
    const unsigned short* c1h = wsu + OFF_C1(i);
    f32x4 h0 = binit(cb1[i*HD + col]), h1 = h0, h2 = h0;
    gemmAh_hb3K(h0, h1, h2, SM, CEN, c1h, 256, col, 0,   lane);
    gemmAh_hb3K(h0, h1, h2, SM, COV, c1h, 256, col, 128, lane);
    stH(SM, CH, 0, lane, col, lrelu4(h0));
    stH(SM, CH, 1, lane, col, lrelu4(h1));
    stH(SM, CH, 2, lane, col, lrelu4(h2));
  }
  __syncthreads();
  // R6: q = h @ cW2 + cb2 (per-row dot, hi-only h), guarded out store
  if (drow < ROWS && gb0 + drow < BATCH){
    int sw4 = (drow & 7) << 4;
    const unsigned char* hb = SM + CH + drow * 256;
    short8 ha = *(const short8*)(hb + (dcb ^ sw4));
    short8 hbf = *(const short8*)(hb + ((dcb + 16) ^ sw4));
    float q0 = 0.f, q1 = 0.f;
    #pragma unroll
    for (int e = 0; e < 8; ++e){
      int d = (lane & 7) * 16 + e;
      float hv = bf2f((unsigned short)ha[e]);
      q0 = fmaf(hv, cW2[(i * HD + d) * 2 + 0], q0);
      q1 = fmaf(hv, cW2[(i * HD + d) * 2 + 1], q1);
    }
    #pragma unroll
    for (int e = 0; e < 8; ++e){
      int d = (lane & 7) * 16 + 8 + e;
      float hv = bf2f((unsigned short)hbf[e]);
      q0 = fmaf(hv, cW2[(i * HD + d) * 2 + 0], q0);
      q1 = fmaf(hv, cW2[(i * HD + d) * 2 + 1], q1);
    }
    RED8(q0) RED8(q1)
    if ((lane & 7) == 0){
      out[((size_t)i * BATCH + gb0 + drow) * 2 + 0] = q0 + cb2[i * 2 + 0];
      out[((size_t)i * BATCH + gb0 + drow) * 2 + 1] = q1 + cb2[i * 2 + 1];
    }
  }
}

// ------------------------------------------------------------ launch -----
extern "C" void kernel_launch(void* const* d_in, const int* in_sizes, int n_in,
                              void* d_out, int out_size, void* d_ws, size_t ws_size,
                              hipStream_t stream) {
  const float* s       = (const float*)d_in[0];
  const float* a       = (const float*)d_in[1];
  const float* en_W    = (const float*)d_in[2];
  const float* en_b    = (const float*)d_in[3];
  const float* oa_W    = (const float*)d_in[4];
  const float* oa_b    = (const float*)d_in[5];
  const float* goal_W  = (const float*)d_in[6];
  const float* goal_b  = (const float*)d_in[7];
  const float* akey_W  = (const float*)d_in[8];
  const float* asel_W  = (const float*)d_in[9];
  const float* aval_W  = (const float*)d_in[10];
  const float* aval_b  = (const float*)d_in[11];
  const float* merge_W = (const float*)d_in[12];
  const float* merge_b = (const float*)d_in[13];
  const float* senc_W  = (const float*)d_in[14];
  const float* senc_b  = (const float*)d_in[15];
  const float* ckey_W  = (const float*)d_in[16];
  const float* csel_W  = (const float*)d_in[17];
  const float* cval_W  = (const float*)d_in[18];
  const float* cval_b  = (const float*)d_in[19];
  const float* cW1     = (const float*)d_in[20];
  const float* cb1     = (const float*)d_in[21];
  const float* cW2     = (const float*)d_in[22];
  const float* cb2     = (const float*)d_in[23];
  unsigned char* wsc = (unsigned char*)d_ws;
  float* F = (float*)(wsc + WSB_F);
  unsigned short* wsu = (unsigned short*)(wsc + WSB_W);
  float* out = (float*)d_out;

  // stats partials live at the head of the sa_g region (time-shared:
  // consumed by fuse_mats before actor_kernel overwrites it)
  float* partial = (float*)(wsc + WSB_SA);

  stats_partial_kernel<<<384, 256, 0, stream>>>(s, a, partial);
  fuse_mats_kernel<<<dim3(HD, 4), HD, 0, stream>>>(
      asel_W, akey_W, csel_W, ckey_W, F,
      (const float*)partial, (float*)(wsc + WSB_STATS));
  prep_split_kernel<<<dim3(336, 16), 256, 0, stream>>>(
      F, aval_W, cval_W, merge_W, cW1, cW2, en_W, oa_W, goal_W, senc_W, wsu);

  unsigned short* sa_g = (unsigned short*)(wsc + WSB_SA);
  actor_kernel<<<dim3(NBLK, NAG), 512, 0, stream>>>(
      s, a, en_b, oa_b, goal_b, aval_b, merge_b,
      (const unsigned char*)wsc, sa_g);
  critic_kernel<<<dim3(NBLK, NAG), 512, 0, stream>>>(
      s, a, senc_b, cval_b, cb1, cW2, cb2,
      (const unsigned char*)wsc, (const unsigned short*)sa_g, out);
}

// Round 19
// 173.391 us; speedup vs baseline: 1.3163x; 1.0321x over previous
//
#include <hip/hip_runtime.h>
#include <hip/hip_bf16.h>

#define NAG 3
#define BATCH 32768
#define HD 128
#define SD 18
#define ROWS 48
#define NBLK 683
#define PADB (NBLK * ROWS)     // 32784
#define EPSV 1e-5f
#define SCALE 0.08838834764831845f

typedef __attribute__((ext_vector_type(8))) short short8;
typedef __attribute__((ext_vector_type(4))) float f32x4;

// ---------------- ws byte layout ----------------
#define WSB_STATS 0
#define WSB_F     1024
#define WSB_W     197632
#define OFF_FT0 0
#define OFF_FT1 32768
#define OFF_MT  65536
#define OFF_AV0 98304
#define OFF_AV1 131072
#define OFF_CV  163840
#define OFF_MG(n) (196608 + (n)*98304)
#define OFF_C1(n) (491520 + (n)*65536)
#define OFF_C2(n) (688128 + (n)*4096)
#define OFF_SW(n) (700416 + (n)*57344)
#define WSB_SA  2097152
// stats partials time-share the first 61.4KB of the sa_g region.
#define SA_BYTES_P ((size_t)NAG * PADB * HD * 2)

__device__ __forceinline__ float lrelu(float x){ return x >= 0.0f ? x : 0.01f * x; }
__device__ __forceinline__ f32x4 lrelu4(f32x4 v){
  f32x4 r; r[0]=lrelu(v[0]); r[1]=lrelu(v[1]); r[2]=lrelu(v[2]); r[3]=lrelu(v[3]); return r;
}
__device__ __forceinline__ f32x4 binit(float b){ f32x4 c; c[0]=b;c[1]=b;c[2]=b;c[3]=b; return c; }
__device__ __forceinline__ unsigned short f2bf(float f){
  __hip_bfloat16 h = __float2bfloat16(f);     // HW v_cvt (RNE)
  return *reinterpret_cast<unsigned short*>(&h);
}
__device__ __forceinline__ float bf2f(unsigned short h){
  return __uint_as_float(((unsigned int)h) << 16);
}

// ---------------- prep: batch stats (384 blocks, atomic-free partials) ----------------
__global__ void stats_partial_kernel(const float* __restrict__ s,
                                     const float* __restrict__ a,
                                     float* __restrict__ partial){
  const int n = blockIdx.x >> 7;
  const int chunk = blockIdx.x & 127;
  const int t = threadIdx.x, lane = t & 63, wave = t >> 6;
  const int rows = BATCH / 128;
  const int b0 = chunk * rows;
  float sum[20], sq[20];
  #pragma unroll
  for (int c = 0; c < 20; ++c){ sum[c] = 0.f; sq[c] = 0.f; }
  {
    int b = b0 + t;
    const float* row = s + ((size_t)n * BATCH + b) * SD;
    #pragma unroll
    for (int c = 0; c < SD; ++c){ float v = row[c]; sum[c] += v; sq[c] += v * v; }
    const float* ra = a + ((size_t)n * BATCH + b) * 2;
    #pragma unroll
    for (int c = 0; c < 2; ++c){ float v = ra[c]; sum[SD + c] += v; sq[SD + c] += v * v; }
  }
  #pragma unroll
  for (int c = 0; c < 20; ++c){
    #pragma unroll
    for (int off = 1; off < 64; off <<= 1){
      sum[c] += __shfl_xor(sum[c], off);
      sq[c]  += __shfl_xor(sq[c],  off);
    }
  }
  __shared__ float red[4][40];
  if (lane == 0){
    #pragma unroll
    for (int c = 0; c < 20; ++c){ red[wave][c*2] = sum[c]; red[wave][c*2+1] = sq[c]; }
  }
  __syncthreads();
  if (t < 40){
    float v = red[0][t] + red[1][t] + red[2][t] + red[3][t];
    partial[((size_t)(n * 128 + chunk)) * 40 + t] = v;
  }
}

// ---------------- prep: F_m = sel @ key^T + stats finalize ----------------
__global__ void fuse_mats_kernel(const float* __restrict__ asel, const float* __restrict__ akey,
                                 const float* __restrict__ csel, const float* __restrict__ ckey,
                                 float* __restrict__ F, const float* __restrict__ partial,
                                 float* __restrict__ stats){
  const int m  = blockIdx.y;
  if (m == 3){
    if (blockIdx.x == 0){
      int i = threadIdx.x;
      if (i < 60){
        int n = i / 20, c = i % 20;
        float S = 0.f, SQ = 0.f;
        const float* p = partial + (size_t)n * 128 * 40 + c * 2;
        #pragma unroll 4
        for (int ch = 0; ch < 128; ++ch){
          S  += p[(size_t)ch * 40 + 0];
          SQ += p[(size_t)ch * 40 + 1];
        }
        float mean = S / (float)BATCH;
        float var = SQ / (float)BATCH - mean * mean;
        stats[i * 2 + 0] = mean;
        stats[i * 2 + 1] = 1.0f / sqrtf(var + EPSV);
      }
    }
    return;
  }
  const int h1 = blockIdx.x;
  const int h2 = threadIdx.x;
  const float* A; const float* Bm;
  if (m == 0){ A = asel;            Bm = akey; }
  else if (m == 1){ A = asel + HD*HD; Bm = akey + HD*HD; }
  else { A = csel; Bm = ckey; }
  const float* arow = A + h1 * HD;
  const float* brow = Bm + h2 * HD;
  float acc = 0.f;
  #pragma unroll 4
  for (int d = 0; d < HD; ++d) acc = fmaf(arow[d], brow[d], acc);
  F[m * HD * HD + h1 * HD + h2] = acc;
}

// ---------------- prep: all weight splits + smallpack ----------------
__global__ void prep_split_kernel(const float* __restrict__ F, const float* __restrict__ aval_W,
                                  const float* __restrict__ cval_W, const float* __restrict__ merge_W,
                                  const float* __restrict__ cW1, const float* __restrict__ cW2,
                                  const float* __restrict__ en_W, const float* __restrict__ oa_W,
                                  const float* __restrict__ goal_W, const float* __restrict__ senc_W,
                                  unsigned short* __restrict__ wsu){
  const int job = blockIdx.y;
  const int idx = blockIdx.x * 256 + threadIdx.x;
  if (job == 15){
    if (idx >= 3 * 896 * 32) return;
    int k = idx & 31; int c = (idx >> 5) % 896; int n = idx / (896 * 32);
    int tt = c >> 7, cc = c & 127;
    float v = 0.f;
    if (tt == 0){
      if (k < 4) v = en_W[(size_t)(n*6 + k)*128 + cc];
      else if (k == 18 || k == 19) v = en_W[(size_t)(n*6 + 4 + (k-18))*128 + cc];
    } else if (tt <= 2){
      int j = tt - 1; int kk = k - (4 + 4*j);
      if (kk >= 0 && kk < 4) v = oa_W[(size_t)(n*4 + kk)*128 + cc];
    } else if (tt <= 5){
      int j = tt - 3; int kk = k - (12 + 2*j);
      if (kk >= 0 && kk < 2) v = goal_W[(size_t)(n*2 + kk)*128 + cc];
    } else {
      if (k < 18) v = senc_W[(size_t)(n*18 + k)*128 + cc];
    }
    unsigned short hi = f2bf(v); float lo = v - bf2f(hi);
    unsigned short* dh = wsu + OFF_SW(n);
    dh[c * 32 + k] = hi;
    dh[28672 + c * 32 + k] = f2bf(lo);
    return;
  }
  const float* src; unsigned short* dh; int K = 128, Csrc = 128, Cdst = 128, loff = 16384;
  switch (job){
    case 0: src = F;              dh = wsu + OFF_FT0; break;
    case 1: src = F + 16384;      dh = wsu + OFF_FT1; break;
    case 2: src = F + 32768;      dh = wsu + OFF_MT;  break;
    case 3: src = aval_W;         dh = wsu + OFF_AV0; break;
    case 4: src = aval_W + 16384; dh = wsu + OFF_AV1; break;
    case 5: src = cval_W;         dh = wsu + OFF_CV;  break;
    case 6: case 7: case 8: {
      int n = job - 6; src = merge_W + (size_t)n * 49152; dh = wsu + OFF_MG(n);
      K = 384; loff = 49152; } break;
    case 9: case 10: case 11: {
      int n = job - 9; src = cW1 + (size_t)n * 32768; dh = wsu + OFF_C1(n);
      K = 256; loff = 32768; } break;
    default: {
      int n = job - 12; src = cW2 + (size_t)n * 256; dh = wsu + OFF_C2(n);
      Csrc = 2; Cdst = 16; loff = 2048; } break;
  }
  if (idx >= K * Cdst) return;
  int k = idx / Cdst, c = idx - k * Cdst;
  float v = (c < Csrc) ? src[(size_t)k * Csrc + c] : 0.f;
  unsigned short hi = f2bf(v);
  dh[(size_t)c * K + k] = hi;
  dh[loff + (size_t)c * K + k] = f2bf(v - bf2f(hi));
}

// ---------------- MFMA helpers ----------------
__device__ __forceinline__ short8 ldAh(const unsigned char* sm, int base, int mi, int ks, int lane){
  int row = mi * 16 + (lane & 15);
  int bc  = ks * 64 + ((lane >> 4) << 4);
  return *(const short8*)(sm + base + row * 256 + (bc ^ ((row & 7) << 4)));
}
__device__ __forceinline__ short8 ldA32h(const unsigned char* sm, int base, int mi, int lane){
  int row = mi * 16 + (lane & 15);
  int bc  = (lane >> 4) << 4;
  return *(const short8*)(sm + base + row * 64 + (bc ^ ((row & 3) << 4)));
}

#define MM1(acc, ah, bh) \
  acc = __builtin_amdgcn_mfma_f32_16x16x32_bf16(ah, bh, acc, 0, 0, 0);

// hi-A, hi-B small encoder: 1 MFMA/mt
__device__ __forceinline__ void gemmS3_hh(f32x4& c0, f32x4& c1, f32x4& c2,
                                          const unsigned char* sm, int abase,
                                          const unsigned short* wh, int bcol, int lane){
  const size_t bb = (size_t)bcol * 32 + ((lane >> 4) << 3);
  const short8 bh = *(const short8*)(wh + bb);
  MM1(c0, ldA32h(sm, abase, 0, lane), bh);
  MM1(c1, ldA32h(sm, abase, 1, lane), bh);
  MM1(c2, ldA32h(sm, abase, 2, lane), bh);
}
__device__ __forceinline__ void gemmAW2_3(f32x4& k0, f32x4& k1, f32x4& k2,
                                          f32x4& m0, f32x4& m1, f32x4& m2,
                                          const unsigned char* sm, int abase,
                                          const unsigned short* wh0, const unsigned short* wh1,
                                          int bcol, int lane){
  const size_t bb = (size_t)bcol * 128 + ((lane >> 4) << 3);
  #pragma unroll
  for (int ks = 0; ks < 4; ++ks){
    short8 a0 = ldAh(sm, abase, 0, ks, lane);
    short8 a1 = ldAh(sm, abase, 1, ks, lane);
    short8 a2 = ldAh(sm, abase, 2, ks, lane);
    const short8 b0 = *(const short8*)(wh0 + bb + ks * 32);
    const short8 b1 = *(const short8*)(wh1 + bb + ks * 32);
    MM1(k0, a0, b0); MM1(k1, a1, b0); MM1(k2, a2, b0);
    MM1(m0, a0, b1); MM1(m1, a1, b1); MM1(m2, a2, b1);
  }
}
__device__ __forceinline__ void gemmA2s3(f32x4& c0, f32x4& c1, f32x4& c2,
                                         f32x4& d0, f32x4& d1, f32x4& d2,
                                         const unsigned char* sm, int a0b, int a1b,
                                         const unsigned short* wh, int bcol, int lane){
  const size_t bb = (size_t)bcol * 128 + ((lane >> 4) << 3);
  #pragma unroll
  for (int ks = 0; ks < 4; ++ks){
    const short8 bh = *(const short8*)(wh + bb + ks * 32);
    short8 x;
    x = ldAh(sm, a0b, 0, ks, lane); MM1(c0, x, bh);
    x = ldAh(sm, a0b, 1, ks, lane); MM1(c1, x, bh);
    x = ldAh(sm, a0b, 2, ks, lane); MM1(c2, x, bh);
    x = ldAh(sm, a1b, 0, ks, lane); MM1(d0, x, bh);
    x = ldAh(sm, a1b, 1, ks, lane); MM1(d1, x, bh);
    x = ldAh(sm, a1b, 2, ks, lane); MM1(d2, x, bh);
  }
}
__device__ __forceinline__ void gemmA3s3(f32x4& c0, f32x4& c1, f32x4& c2,
                                         f32x4& d0, f32x4& d1, f32x4& d2,
                                         f32x4& e0, f32x4& e1, f32x4& e2,
                                         const unsigned char* sm, int a0b, int a1b, int a2b,
                                         const unsigned short* wh, int bcol, int lane){
  const size_t bb = (size_t)bcol * 128 + ((lane >> 4) << 3);
  #pragma unroll
  for (int ks = 0; ks < 4; ++ks){
    const short8 bh = *(const short8*)(wh + bb + ks * 32);
    short8 x;
    x = ldAh(sm, a0b, 0, ks, lane); MM1(c0, x, bh);
    x = ldAh(sm, a0b, 1, ks, lane); MM1(c1, x, bh);
    x = ldAh(sm, a0b, 2, ks, lane); MM1(c2, x, bh);
    x = ldAh(sm, a1b, 0, ks, lane); MM1(d0, x, bh);
    x = ldAh(sm, a1b, 1, ks, lane); MM1(d1, x, bh);
    x = ldAh(sm, a1b, 2, ks, lane); MM1(d2, x, bh);
    x = ldAh(sm, a2b, 0, ks, lane); MM1(e0, x, bh);
    x = ldAh(sm, a2b, 1, ks, lane); MM1(e1, x, bh);
    x = ldAh(sm, a2b, 2, ks, lane); MM1(e2, x, bh);
  }
}
__device__ __forceinline__ void gemmAh_hb3K(f32x4& c0, f32x4& c1, f32x4& c2,
                                            const unsigned char* sm, int abase,
                                            const unsigned short* wh,
                                            int K, int bcol, int kBase, int lane){
  const size_t bb = (size_t)bcol * K + kBase + ((lane >> 4) << 3);
  #pragma unroll
  for (int ks = 0; ks < 4; ++ks){
    const short8 bh = *(const short8*)(wh + bb + ks * 32);
    short8 a;
    a = ldAh(sm, abase, 0, ks, lane); MM1(c0, a, bh);
    a = ldAh(sm, abase, 1, ks, lane); MM1(c1, a, bh);
    a = ldAh(sm, abase, 2, ks, lane); MM1(c2, a, bh);
  }
}
__device__ __forceinline__ void gemmAh_hb3(f32x4& c0, f32x4& c1, f32x4& c2,
                                           const unsigned char* sm, int abase,
                                           const unsigned short* wh, int bcol, int lane){
  const size_t bb = (size_t)bcol * 128 + ((lane >> 4) << 3);
  #pragma unroll
  for (int ks = 0; ks < 4; ++ks){
    const short8 bh = *(const short8*)(wh + bb + ks * 32);
    short8 a;
    a = ldAh(sm, abase, 0, ks, lane); MM1(c0, a, bh);
    a = ldAh(sm, abase, 1, ks, lane); MM1(c1, a, bh);
    a = ldAh(sm, abase, 2, ks, lane); MM1(c2, a, bh);
  }
}
// diag(selk_tile @ slice_tile^T) via MFMA: p[row] for 16 rows of m-tile mt;
// diagonal lanes apply expf and write eP[mt*16+row].
__device__ __forceinline__ void diagExp(const unsigned char* sm, int kbase, int sbase,
                                        int mt, int lane, float* eP){
  f32x4 c = binit(0.f);
  #pragma unroll
  for (int ks = 0; ks < 4; ++ks){
    short8 a = ldAh(sm, kbase, mt, ks, lane);
    short8 b = ldAh(sm, sbase, mt, ks, lane);
    MM1(c, a, b);
  }
  int lo = lane & 15, g = lane >> 4;
  if ((lo >> 2) == g){
    int r = lo & 3;
    float pv = (r == 0) ? c[0] : (r == 1) ? c[1] : (r == 2) ? c[2] : c[3];
    eP[mt * 16 + lo] = __expf(pv * SCALE);
  }
}

// stores
__device__ __forceinline__ void stH(unsigned char* sm, int base, int mi, int lane, int col, f32x4 v){
  #pragma unroll
  for (int r = 0; r < 4; ++r){
    int row = mi * 16 + ((lane >> 4) << 2) + r;
    int off = base + row * 256 + ((col * 2) ^ ((row & 7) << 4));
    *(unsigned short*)(sm + off) = f2bf(v[r]);
  }
}
#define RED8(p) { p += __shfl_xor(p, 1); p += __shfl_xor(p, 2); p += __shfl_xor(p, 4); }

// ======================================================================
// PATH A: actor kernel — grid (NBLK, NAG), 512 threads, ROWS=48, 77.6KB LDS
// (XN hi-only; MFMA-diag logits)
// ======================================================================
__global__ __launch_bounds__(512, 4) void actor_kernel(
    const float* __restrict__ s, const float* __restrict__ a,
    const float* __restrict__ en_b, const float* __restrict__ oa_b,
    const float* __restrict__ goal_b, const float* __restrict__ aval_b,
    const float* __restrict__ merge_b, const unsigned char* __restrict__ wsc,
    unsigned short* __restrict__ sa_g)
{
  __shared__ __align__(16) unsigned char SM[77568];
  const int AXN = 0, AEN = 3072, AOV = 15360, ASK = 27648;
  const int SLB0 = 39936, SLB1 = 52224, SLB2 = 64512, AEP = 76800;
  const int t = threadIdx.x, lane = t & 63, wave = t >> 6;
  const int col = wave * 16 + (lane & 15);
  const int n = blockIdx.y;
  const int gb0 = blockIdx.x * ROWS;
  const float* stats = (const float*)(wsc + WSB_STATS);
  const unsigned short* wsu = (const unsigned short*)(wsc + WSB_W);
  const unsigned short* swh = wsu + OFF_SW(n);
  float* eP0 = (float*)(SM + AEP);
  float* eP1 = eP0 + 48;
  float* eP2 = eP0 + 96;
  const f32x4 Z = binit(0.f);
  const int r0base = (lane >> 4) << 2;

  // init: stage normalized XN (hi-only, K=32), clamped reads
  if (t < ROWS){
    int row = t;
    size_t gb = (size_t)gb0 + row;
    if (gb >= BATCH) gb = BATCH - 1;
    const float* st = stats + n * 40;
    const float* srow = s + ((size_t)n * BATCH + gb) * SD;
    const float* arow = a + ((size_t)n * BATCH + gb) * 2;
    #pragma unroll
    for (int c = 0; c < 32; ++c){
      float v = 0.f;
      if (c < 18) v = (srow[c] - st[c*2]) * st[c*2+1];
      else if (c < 20) v = (arow[c-18] - st[c*2]) * st[c*2+1];
      int off = AXN + row * 64 + ((c * 2) ^ ((row & 3) << 4));
      *(unsigned short*)(SM + off) = f2bf(v);
    }
  }
  __syncthreads();
  // R0: en_enc -> AEN ; oa slices -> SLB0, SLB1 (hi-A hi-B)
  {
    f32x4 c0 = binit(en_b[n*HD + col]), c1 = c0, c2 = c0;
    gemmS3_hh(c0, c1, c2, SM, AXN, swh, col, lane);
    stH(SM, AEN, 0, lane, col, lrelu4(c0));
    stH(SM, AEN, 1, lane, col, lrelu4(c1));
    stH(SM, AEN, 2, lane, col, lrelu4(c2));
    const float bb = oa_b[n*HD + col];
    c0 = binit(bb); c1 = c0; c2 = c0;
    gemmS3_hh(c0, c1, c2, SM, AXN, swh, 128 + col, lane);
    stH(SM, SLB0, 0, lane, col, lrelu4(c0));
    stH(SM, SLB0, 1, lane, col, lrelu4(c1));
    stH(SM, SLB0, 2, lane, col, lrelu4(c2));
    c0 = binit(bb); c1 = c0; c2 = c0;
    gemmS3_hh(c0, c1, c2, SM, AXN, swh, 256 + col, lane);
    stH(SM, SLB1, 0, lane, col, lrelu4(c0));
    stH(SM, SLB1, 1, lane, col, lrelu4(c1));
    stH(SM, SLB1, 2, lane, col, lrelu4(c2));
  }
  __syncthreads();
  // R1: selk0 -> AOV, selk1 -> ASK (hi-B, standard layout)
  {
    f32x4 k0 = Z, k1 = Z, k2 = Z, m0 = Z, m1 = Z, m2 = Z;
    gemmAW2_3(k0, k1, k2, m0, m1, m2, SM, AEN,
              wsu + OFF_FT0, wsu + OFF_FT1, col, lane);
    stH(SM, AOV, 0, lane, col, k0); stH(SM, AOV, 1, lane, col, k1); stH(SM, AOV, 2, lane, col, k2);
    stH(SM, ASK, 0, lane, col, m0); stH(SM, ASK, 1, lane, col, m1); stH(SM, ASK, 2, lane, col, m2);
  }
  __syncthreads();
  // R2: oa vals + MFMA-diag logits + exp
  f32x4 va0, va1, va2, vb0, vb1, vb2;
  {
    const float vb = aval_b[col];
    va0 = binit(vb); va1 = va0; va2 = va0; vb0 = va0; vb1 = va0; vb2 = va0;
    gemmA2s3(va0, va1, va2, vb0, vb1, vb2, SM, SLB0, SLB1, wsu + OFF_AV0, col, lane);
    // 6 units: j in {0,1}, mt in {0..2}
    for (int u = wave; u < 6; u += 8){
      int j = u / 3, mt = u - j * 3;
      diagExp(SM, AOV, j ? SLB1 : SLB0, mt, lane, j ? eP1 : eP0);
    }
  }
  __syncthreads();
  // R3: ov0 -> AOV ; goal slices g0,g1,g2 -> SLB0,1,2 (hi-A hi-B)
  {
    f32x4 o;
    #pragma unroll
    for (int r = 0; r < 4; ++r){
      int mr = r0base + r;
      o[r] = (eP0[mr] * lrelu(va0[r]) + eP1[mr] * lrelu(vb0[r])) / (eP0[mr] + eP1[mr]);
    }
    stH(SM, AOV, 0, lane, col, o);
    #pragma unroll
    for (int r = 0; r < 4; ++r){
      int mr = 16 + r0base + r;
      o[r] = (eP0[mr] * lrelu(va1[r]) + eP1[mr] * lrelu(vb1[r])) / (eP0[mr] + eP1[mr]);
    }
    stH(SM, AOV, 1, lane, col, o);
    #pragma unroll
    for (int r = 0; r < 4; ++r){
      int mr = 32 + r0base + r;
      o[r] = (eP0[mr] * lrelu(va2[r]) + eP1[mr] * lrelu(vb2[r])) / (eP0[mr] + eP1[mr]);
    }
    stH(SM, AOV, 2, lane, col, o);
    const float bb = goal_b[n*HD + col];
    f32x4 c0 = binit(bb), c1 = c0, c2 = c0;
    gemmS3_hh(c0, c1, c2, SM, AXN, swh, 384 + col, lane);
    stH(SM, SLB0, 0, lane, col, lrelu4(c0));
    stH(SM, SLB0, 1, lane, col, lrelu4(c1));
    stH(SM, SLB0, 2, lane, col, lrelu4(c2));
    c0 = binit(bb); c1 = c0; c2 = c0;
    gemmS3_hh(c0, c1, c2, SM, AXN, swh, 512 + col, lane);
    stH(SM, SLB1, 0, lane, col, lrelu4(c0));
    stH(SM, SLB1, 1, lane, col, lrelu4(c1));
    stH(SM, SLB1, 2, lane, col, lrelu4(c2));
    c0 = binit(bb); c1 = c0; c2 = c0;
    gemmS3_hh(c0, c1, c2, SM, AXN, swh, 640 + col, lane);
    stH(SM, SLB2, 0, lane, col, lrelu4(c0));
    stH(SM, SLB2, 1, lane, col, lrelu4(c1));
    stH(SM, SLB2, 2, lane, col, lrelu4(c2));
  }
  __syncthreads();
  // R4: goal vals + MFMA-diag logits (selk1 vs g0,g1,g2) + exps
  f32x4 g0m0, g0m1, g0m2, g1m0, g1m1, g1m2, g2m0, g2m1, g2m2;
  {
    const float vb = aval_b[HD + col];
    g0m0 = binit(vb); g0m1 = g0m0; g0m2 = g0m0;
    g1m0 = g0m0; g1m1 = g0m0; g1m2 = g0m0;
    g2m0 = g0m0; g2m1 = g0m0; g2m2 = g0m0;
    gemmA3s3(g0m0, g0m1, g0m2, g1m0, g1m1, g1m2, g2m0, g2m1, g2m2,
             SM, SLB0, SLB1, SLB2, wsu + OFF_AV1, col, lane);
    // 9 units: j in {0,1,2}, mt in {0..2}
    for (int u = wave; u < 9; u += 8){
      int j = u / 3, mt = u - j * 3;
      diagExp(SM, ASK, SLB0 + j * 12288, mt, lane, eP0 + j * 48);
    }
  }
  __syncthreads();
  // R5: ov1 -> SLB0
  {
    f32x4 o;
    #pragma unroll
    for (int r = 0; r < 4; ++r){
      int mr = r0base + r;
      o[r] = ((eP0[mr] * lrelu(g0m0[r]) + eP1[mr] * lrelu(g1m0[r]))
              + eP2[mr] * lrelu(g2m0[r])) / ((eP0[mr] + eP1[mr]) + eP2[mr]);
    }
    stH(SM, SLB0, 0, lane, col, o);
    #pragma unroll
    for (int r = 0; r < 4; ++r){
      int mr = 16 + r0base + r;
      o[r] = ((eP0[mr] * lrelu(g0m1[r]) + eP1[mr] * lrelu(g1m1[r]))
              + eP2[mr] * lrelu(g2m1[r])) / ((eP0[mr] + eP1[mr]) + eP2[mr]);
    }
    stH(SM, SLB0, 1, lane, col, o);
    #pragma unroll
    for (int r = 0; r < 4; ++r){
      int mr = 32 + r0base + r;
      o[r] = ((eP0[mr] * lrelu(g0m2[r]) + eP1[mr] * lrelu(g1m2[r]))
              + eP2[mr] * lrelu(g2m2[r])) / ((eP0[mr] + eP1[mr]) + eP2[mr]);
    }
    stH(SM, SLB0, 2, lane, col, o);
  }
  __syncthreads();
  // R6: merge (hi-B) -> SLB1
  {
    const unsigned short* mh = wsu + OFF_MG(n);
    f32x4 c0 = binit(merge_b[n*HD + col]), c1 = c0, c2 = c0;
    gemmAh_hb3K(c0, c1, c2, SM, AEN,  mh, 384, col, 0,   lane);
    gemmAh_hb3K(c0, c1, c2, SM, AOV,  mh, 384, col, 128, lane);
    gemmAh_hb3K(c0, c1, c2, SM, SLB0, mh, 384, col, 256, lane);
    stH(SM, SLB1, 0, lane, col, lrelu4(c0));
    stH(SM, SLB1, 1, lane, col, lrelu4(c1));
    stH(SM, SLB1, 2, lane, col, lrelu4(c2));
  }
  __syncthreads();
  // R7: coalesced copy SLB1 -> sa_g (padded)
  for (int idx = t; idx < ROWS * 16; idx += 512){
    int row = idx >> 4, ch = idx & 15;
    short8 u = *(const short8*)(SM + SLB1 + row * 256 + ((ch * 16) ^ ((row & 7) << 4)));
    *(short8*)(sa_g + ((size_t)n * PADB + gb0 + row) * HD + ch * 8) = u;
  }
}

// ======================================================================
// PATH A: critic kernel — grid (NBLK, NAG=i), 512 threads, ROWS=48, 52.6KB LDS
// (MFMA-diag logits)
// ======================================================================
__global__ __launch_bounds__(512, 4) void critic_kernel(
    const float* __restrict__ s, const float* __restrict__ a,
    const float* __restrict__ senc_b, const float* __restrict__ cval_b,
    const float* __restrict__ cb1, const float* __restrict__ cW2,
    const float* __restrict__ cb2, const unsigned char* __restrict__ wsc,
    const unsigned short* __restrict__ sa_g, float* __restrict__ out)
{
  __shared__ __align__(16) unsigned char SM[52608];
  const int CXN = 0, CEN = 3072, CSMo = 15360, CSA = 27648;
  const int COV = 15360, CH = 27648, CLW = 52224;
  const int t = threadIdx.x, lane = t & 63, wave = t >> 6;
  const int col = wave * 16 + (lane & 15);
  const int i = blockIdx.y;
  const int gb0 = blockIdx.x * ROWS;
  const int j0 = (i == 0) ? 1 : 0;
  const int j1 = (i == 2) ? 1 : 2;
  const float* stats = (const float*)(wsc + WSB_STATS);
  const unsigned short* wsu = (const unsigned short*)(wsc + WSB_W);
  const unsigned short* swh = wsu + OFF_SW(i);
  const f32x4 Z = binit(0.f);
  const int drow = wave * 8 + (lane >> 3);
  const int dcb  = (lane & 7) * 32;
  const int r0base = (lane >> 4) << 2;

  // R0: stage XN_i (hi-only, clamped) + copy sa_j0/j1 -> LDS (hi, swz)
  if (t < ROWS){
    int row = t;
    size_t gb = (size_t)gb0 + row;
    if (gb >= BATCH) gb = BATCH - 1;
    const float* st = stats + i * 40;
    const float* srow = s + ((size_t)i * BATCH + gb) * SD;
    const float* arow = a + ((size_t)i * BATCH + gb) * 2;
    #pragma unroll
    for (int c = 0; c < 32; ++c){
      float v = 0.f;
      if (c < 18) v = (srow[c] - st[c*2]) * st[c*2+1];
      else if (c < 20) v = (arow[c-18] - st[c*2]) * st[c*2+1];
      int off = CXN + row * 64 + ((c * 2) ^ ((row & 3) << 4));
      *(unsigned short*)(SM + off) = f2bf(v);
    }
  }
  for (int idx = t; idx < 2 * ROWS * 16; idx += 512){
    int tile = idx >= ROWS * 16;
    int k = idx - tile * ROWS * 16;
    int row = k >> 4, ch = k & 15;
    int j = tile ? j1 : j0;
    short8 u = *(const short8*)(sa_g + ((size_t)j * PADB + gb0 + row) * HD + ch * 8);
    *(short8*)(SM + CSA + tile * 12288 + row * 256 + ((ch * 16) ^ ((row & 7) << 4))) = u;
  }
  __syncthreads();
  // R1: s_enc -> CEN (hi-A hi-B)
  {
    f32x4 c0 = binit(senc_b[i*HD + col]), c1 = c0, c2 = c0;
    gemmS3_hh(c0, c1, c2, SM, CXN, swh, 768 + col, lane);
    stH(SM, CEN, 0, lane, col, lrelu4(c0));
    stH(SM, CEN, 1, lane, col, lrelu4(c1));
    stH(SM, CEN, 2, lane, col, lrelu4(c2));
  }
  __syncthreads();
  // R2: selsM = s_enc @ M (hi-B) -> CSM (standard layout)
  {
    f32x4 k0 = Z, k1 = Z, k2 = Z;
    gemmAh_hb3(k0, k1, k2, SM, CEN, wsu + OFF_MT, col, lane);
    stH(SM, CSMo, 0, lane, col, k0);
    stH(SM, CSMo, 1, lane, col, k1);
    stH(SM, CSMo, 2, lane, col, k2);
  }
  __syncthreads();
  // R3: vals GEMMs + MFMA-diag logits + exp
  f32x4 v00, v01, v02, v10, v11, v12;
  {
    const float vb = cval_b[col];
    v00 = binit(vb); v01 = v00; v02 = v00; v10 = v00; v11 = v00; v12 = v00;
    gemmA2s3(v00, v01, v02, v10, v11, v12, SM, CSA, CSA + 12288,
             wsu + OFF_CV, col, lane);
    float* eW = (float*)(SM + CLW);
    for (int u = wave; u < 6; u += 8){
      int j = u / 3, mt = u - j * 3;
      diagExp(SM, CSMo, CSA + j * 12288, mt, lane, eW + j * 48);
    }
  }
  __syncthreads();
  // R4: ov -> COV (hi; overwrites CSM)
  {
    const float* e0a = (const float*)(SM + CLW);
    const float* e1a = e0a + 48;
    f32x4 o;
    #pragma unroll
    for (int r = 0; r < 4; ++r){
      int mr = r0base + r;
      float inv = 1.f / (e0a[mr] + e1a[mr]);
      o[r] = (e0a[mr] * inv) * lrelu(v00[r]) + (e1a[mr] * inv) * lrelu(v10[r]);
    }
    stH(SM, COV, 0, lane, col, o);
    #pragma unroll
    for (int r = 0; r < 4; ++r){
      int mr = 16 + r0base + r;
      float inv = 1.f / (e0a[mr] + e1a[mr]);
      o[r] = (e0a[mr] * inv) * lrelu(v01[r]) + (e1a[mr] * inv) * lrelu(v11[r]);
    }
    stH(SM, COV, 1, lane, col, o);
    #pragma unroll
    for (int r = 0; r < 4; ++r){
      int mr = 32 + r0base + r;
      float inv = 1.f / (e0a[mr] + e1a[mr]);
      o[r] = (e0a[mr] * inv) * lrelu(v02[r]) + (e1a[mr] * inv) * lrelu(v12[r]);
    }
    stH(SM, COV, 2, lane, col, o);
  }
  __syncthreads();
  // R5: h = lrelu([s_enc|ov] @ cW1 + b) -> CH (hi-only; overwrites CSA)
  {
    const unsigned short* c1h = wsu + OFF_C1(i);
    f32x4 h0 = binit(cb1[i*HD + col]), h1 = h0, h2 = h0;
    gemmAh_hb3K(h0, h1, h2, SM, CEN, c1h, 256, col, 0,   lane);
    gemmAh_hb3K(h0, h1, h2, SM, COV, c1h, 256, col, 128, lane);
    stH(SM, CH, 0, lane, col, lrelu4(h0));
    stH(SM, CH, 1, lane, col, lrelu4(h1));
    stH(SM, CH, 2, lane, col, lrelu4(h2));
  }
  __syncthreads();
  // R6: q = h @ cW2 + cb2 (per-row dot, hi-only h), guarded out store
  if (drow < ROWS && gb0 + drow < BATCH){
    int sw4 = (drow & 7) << 4;
    const unsigned char* hb = SM + CH + drow * 256;
    short8 ha = *(const short8*)(hb + (dcb ^ sw4));
    short8 hbf = *(const short8*)(hb + ((dcb + 16) ^ sw4));
    float q0 = 0.f, q1 = 0.f;
    #pragma unroll
    for (int e = 0; e < 8; ++e){
      int d = (lane & 7) * 16 + e;
      float hv = bf2f((unsigned short)ha[e]);
      q0 = fmaf(hv, cW2[(i * HD + d) * 2 + 0], q0);
      q1 = fmaf(hv, cW2[(i * HD + d) * 2 + 1], q1);
    }
    #pragma unroll
    for (int e = 0; e < 8; ++e){
      int d = (lane & 7) * 16 + 8 + e;
      float hv = bf2f((unsigned short)hbf[e]);
      q0 = fmaf(hv, cW2[(i * HD + d) * 2 + 0], q0);
      q1 = fmaf(hv, cW2[(i * HD + d) * 2 + 1], q1);
    }
    RED8(q0) RED8(q1)
    if ((lane & 7) == 0){
      out[((size_t)i * BATCH + gb0 + drow) * 2 + 0] = q0 + cb2[i * 2 + 0];
      out[((size_t)i * BATCH + gb0 + drow) * 2 + 1] = q1 + cb2[i * 2 + 1];
    }
  }
}

// ------------------------------------------------------------ launch -----
extern "C" void kernel_launch(void* const* d_in, const int* in_sizes, int n_in,
                              void* d_out, int out_size, void* d_ws, size_t ws_size,
                              hipStream_t stream) {
  const float* s       = (const float*)d_in[0];
  const float* a       = (const float*)d_in[1];
  const float* en_W    = (const float*)d_in[2];
  const float* en_b    = (const float*)d_in[3];
  const float* oa_W    = (const float*)d_in[4];
  const float* oa_b    = (const float*)d_in[5];
  const float* goal_W  = (const float*)d_in[6];
  const float* goal_b  = (const float*)d_in[7];
  const float* akey_W  = (const float*)d_in[8];
  const float* asel_W  = (const float*)d_in[9];
  const float* aval_W  = (const float*)d_in[10];
  const float* aval_b  = (const float*)d_in[11];
  const float* merge_W = (const float*)d_in[12];
  const float* merge_b = (const float*)d_in[13];
  const float* senc_W  = (const float*)d_in[14];
  const float* senc_b  = (const float*)d_in[15];
  const float* ckey_W  = (const float*)d_in[16];
  const float* csel_W  = (const float*)d_in[17];
  const float* cval_W  = (const float*)d_in[18];
  const float* cval_b  = (const float*)d_in[19];
  const float* cW1     = (const float*)d_in[20];
  const float* cb1     = (const float*)d_in[21];
  const float* cW2     = (const float*)d_in[22];
  const float* cb2     = (const float*)d_in[23];
  unsigned char* wsc = (unsigned char*)d_ws;
  float* F = (float*)(wsc + WSB_F);
  unsigned short* wsu = (unsigned short*)(wsc + WSB_W);
  float* out = (float*)d_out;

  float* partial = (float*)(wsc + WSB_SA);

  stats_partial_kernel<<<384, 256, 0, stream>>>(s, a, partial);
  fuse_mats_kernel<<<dim3(HD, 4), HD, 0, stream>>>(
      asel_W, akey_W, csel_W, ckey_W, F,
      (const float*)partial, (float*)(wsc + WSB_STATS));
  prep_split_kernel<<<dim3(336, 16), 256, 0, stream>>>(
      F, aval_W, cval_W, merge_W, cW1, cW2, en_W, oa_W, goal_W, senc_W, wsu);

  unsigned short* sa_g = (unsigned short*)(wsc + WSB_SA);
  actor_kernel<<<dim3(NBLK, NAG), 512, 0, stream>>>(
      s, a, en_b, oa_b, goal_b, aval_b, merge_b,
      (const unsigned char*)wsc, sa_g);
  critic_kernel<<<dim3(NBLK, NAG), 512, 0, stream>>>(
      s, a, senc_b, cval_b, cb1, cW2, cb2,
      (const unsigned char*)wsc, (const unsigned short*)sa_g, out);
}